// Round 1
// baseline (1131.415 us; speedup 1.0000x reference)
//
#include <hip/hip_runtime.h>
#include <math.h>

#define BATCH   8
#define CCH     512
#define NHEADS  8
#define HD      64
#define NGROUPS 32
#define CPG     16
#define NSP     4096      // H*W
#define O1      1536      // 3*C
#define NCHUNK  8

// ---------------------------------------------------------------------------
// phi(x) = elu(x) + 1  (alpha=1):  x>0 -> x+1 ; else exp(x)
__device__ __forceinline__ float phi_act(float v) {
    return v > 0.f ? v + 1.f : __expf(v);
}

// ---------------------------------------------------------------------------
// Kernel 1: GroupNorm statistics -> per-(b,c) scale/shift
// grid: B*NGROUPS blocks, 256 threads. Group data is contiguous (16ch*4096).
__global__ __launch_bounds__(256) void gn_stats(const float* __restrict__ x,
                                                const float* __restrict__ gamma,
                                                const float* __restrict__ beta,
                                                float* __restrict__ ss) {
    const int bg = blockIdx.x;            // b*NGROUPS + g
    const int t  = threadIdx.x;
    const float* base = x + (size_t)bg * (CPG * NSP);  // contiguous 65536 floats
    float s = 0.f, s2 = 0.f;
    #pragma unroll 4
    for (int i = 0; i < 64; ++i) {
        float4 v = *(const float4*)(base + (i * 256 + t) * 4);
        s  += v.x + v.y + v.z + v.w;
        s2 += v.x * v.x + v.y * v.y + v.z * v.z + v.w * v.w;
    }
    __shared__ float r1[256], r2[256];
    r1[t] = s; r2[t] = s2;
    __syncthreads();
    for (int off = 128; off > 0; off >>= 1) {
        if (t < off) { r1[t] += r1[t + off]; r2[t] += r2[t + off]; }
        __syncthreads();
    }
    if (t < CPG) {
        const float inv = 1.f / 65536.f;
        float mean = r1[0] * inv;
        float var  = r2[0] * inv - mean * mean;
        float rstd = rsqrtf(var + 1e-5f);
        int b = bg / NGROUPS, g = bg % NGROUPS;
        int c = g * CPG + t;
        float sc = gamma[c] * rstd;
        float sh = beta[c] - mean * sc;
        ss[(b * CCH + c) * 2]     = sc;
        ss[(b * CCH + c) * 2 + 1] = sh;
    }
}

// ---------------------------------------------------------------------------
// Kernel 2: QKV GEMM.  qkv[b,o,n] = sum_c (x[b,c,n]*sc+sh) * w[o,c] + bias[o]
// phi applied for o < 1024 (q and k thirds).
// 64x64 tile, BK=16, 256 threads, 4x4 per thread.
__global__ __launch_bounds__(256) void qkv_gemm(const float* __restrict__ x,
                                                const float* __restrict__ ss,
                                                const float* __restrict__ w,
                                                const float* __restrict__ bias,
                                                float* __restrict__ qkv) {
    const int n0 = blockIdx.x * 64;
    const int o0 = blockIdx.y * 64;
    const int b  = blockIdx.z;
    const int t  = threadIdx.x;
    const int tx = t % 16, ty = t / 16;

    __shared__ float As[16][68];   // [k][o], stride 68: 16B aligned rows, ~2-way writes
    __shared__ float Bs[16][64];   // [k][n]

    float acc[4][4] = {};

    const float* xb  = x  + (size_t)b * CCH * NSP;
    const float* ssb = ss + b * CCH * 2;

    const int la_o = t / 4;          // 0..63
    const int la_c = (t % 4) * 4;    // 0,4,8,12
    const int lb_c = t / 16;         // 0..15
    const int lb_n = (t % 16) * 4;   // 0..60

    for (int k0 = 0; k0 < CCH; k0 += 16) {
        float4 a4 = *(const float4*)(w + (size_t)(o0 + la_o) * CCH + k0 + la_c);
        int c = k0 + lb_c;
        float4 b4 = *(const float4*)(xb + (size_t)c * NSP + n0 + lb_n);
        float sc = ssb[c * 2], sh = ssb[c * 2 + 1];
        b4.x = b4.x * sc + sh; b4.y = b4.y * sc + sh;
        b4.z = b4.z * sc + sh; b4.w = b4.w * sc + sh;
        __syncthreads();
        As[la_c + 0][la_o] = a4.x;
        As[la_c + 1][la_o] = a4.y;
        As[la_c + 2][la_o] = a4.z;
        As[la_c + 3][la_o] = a4.w;
        *(float4*)&Bs[lb_c][lb_n] = b4;
        __syncthreads();
        #pragma unroll
        for (int kk = 0; kk < 16; ++kk) {
            float4 af = *(const float4*)&As[kk][ty * 4];
            float4 bf = *(const float4*)&Bs[kk][tx * 4];
            float av[4] = {af.x, af.y, af.z, af.w};
            float bv[4] = {bf.x, bf.y, bf.z, bf.w};
            #pragma unroll
            for (int i = 0; i < 4; ++i)
                #pragma unroll
                for (int j = 0; j < 4; ++j)
                    acc[i][j] += av[i] * bv[j];
        }
    }
    #pragma unroll
    for (int i = 0; i < 4; ++i) {
        int o = o0 + ty * 4 + i;
        float bs = bias[o];
        float4 r = {acc[i][0] + bs, acc[i][1] + bs, acc[i][2] + bs, acc[i][3] + bs};
        if (o < 2 * CCH) {  // q and k thirds get phi
            r.x = phi_act(r.x); r.y = phi_act(r.y);
            r.z = phi_act(r.z); r.w = phi_act(r.w);
        }
        *(float4*)(qkv + ((size_t)b * O1 + o) * NSP + n0 + tx * 4) = r;
    }
}

// ---------------------------------------------------------------------------
// Kernel 3: partial kv[d][e] = sum_n k[d][n]*v[e][n] and ksum[d], per n-chunk.
// grid: (NCHUNK, 64 bh). Tiles [ch][n] stride 68 in LDS, float2 compute reads.
__global__ __launch_bounds__(256) void kv_partial(const float* __restrict__ qkv,
                                                  float* __restrict__ kv_part,
                                                  float* __restrict__ ks_part) {
    const int chunk = blockIdx.x;
    const int bh    = blockIdx.y;
    const int b = bh / NHEADS, hh = bh % NHEADS;
    const int t = threadIdx.x;
    const int d0 = (t / 16) * 4, e0 = (t % 16) * 4;

    __shared__ float kt[64 * 68];
    __shared__ float vt[64 * 68];

    const float* kbase = qkv + ((size_t)b * O1 + CCH     + hh * HD) * NSP;
    const float* vbase = qkv + ((size_t)b * O1 + 2 * CCH + hh * HD) * NSP;

    float acc[4][4] = {};
    float ks[4] = {};
    const int fl = t * 4;

    for (int nt = 0; nt < 8; ++nt) {
        int nbase = chunk * 512 + nt * 64;
        __syncthreads();
        #pragma unroll
        for (int j = 0; j < 4; ++j) {
            int flat = j * 1024 + fl;
            int dch = flat / 64, nl = flat % 64;
            float4 k4 = *(const float4*)(kbase + (size_t)dch * NSP + nbase + nl);
            float4 v4 = *(const float4*)(vbase + (size_t)dch * NSP + nbase + nl);
            *(float4*)&kt[dch * 68 + nl] = k4;
            *(float4*)&vt[dch * 68 + nl] = v4;
        }
        __syncthreads();
        for (int nl = 0; nl < 64; nl += 2) {
            float2 kf[4], vf[4];
            #pragma unroll
            for (int i = 0; i < 4; ++i) {
                kf[i] = *(const float2*)&kt[(d0 + i) * 68 + nl];
                vf[i] = *(const float2*)&vt[(e0 + i) * 68 + nl];
            }
            #pragma unroll
            for (int i = 0; i < 4; ++i)
                #pragma unroll
                for (int j = 0; j < 4; ++j)
                    acc[i][j] += kf[i].x * vf[j].x + kf[i].y * vf[j].y;
            if ((t % 16) == 0) {
                #pragma unroll
                for (int i = 0; i < 4; ++i) ks[i] += kf[i].x + kf[i].y;
            }
        }
    }
    float* kvp = kv_part + ((size_t)(chunk * 64 + bh)) * HD * HD;
    #pragma unroll
    for (int i = 0; i < 4; ++i) {
        float4 r = {acc[i][0], acc[i][1], acc[i][2], acc[i][3]};
        *(float4*)(kvp + (d0 + i) * HD + e0) = r;
    }
    if ((t % 16) == 0) {
        float4 r = {ks[0], ks[1], ks[2], ks[3]};
        *(float4*)(ks_part + ((size_t)(chunk * 64 + bh)) * HD + d0) = r;
    }
}

// ---------------------------------------------------------------------------
// Kernel 4: reduce the NCHUNK partials.
__global__ __launch_bounds__(256) void kv_reduce(const float* __restrict__ kv_part,
                                                 const float* __restrict__ ks_part,
                                                 float* __restrict__ kv_f,
                                                 float* __restrict__ ks_f) {
    const int idx = blockIdx.x * 256 + threadIdx.x;
    const int NKV = 64 * HD * HD;  // 262144
    if (idx < NKV) {
        float s = 0.f;
        #pragma unroll
        for (int p = 0; p < NCHUNK; ++p) s += kv_part[(size_t)p * NKV + idx];
        kv_f[idx] = s;
    } else if (idx - NKV < 64 * HD) {
        int i2 = idx - NKV;
        float s = 0.f;
        #pragma unroll
        for (int p = 0; p < NCHUNK; ++p) s += ks_part[p * 64 * HD + i2];
        ks_f[i2] = s;
    }
}

// ---------------------------------------------------------------------------
// Kernel 5: out[e][n] = (sum_d q[d][n]*kv[d][e]) / (sum_d q[d][n]*ksum[d] + eps)
// grid: (16 nblk, 64 bh), 256 threads: tx=n(4 cols), eg=e-group(16 rows).
// Writes attn into the (dead) k region of qkv.
__global__ __launch_bounds__(256) void attn_kernel(float* __restrict__ qkv,
                                                   const float* __restrict__ kv_f,
                                                   const float* __restrict__ ks_f) {
    const int nblk = blockIdx.x;
    const int bh   = blockIdx.y;
    const int b = bh / NHEADS, hh = bh % NHEADS;
    const int t = threadIdx.x;
    const int tx = t % 64, eg = t / 64;
    const int n  = nblk * 256 + tx * 4;
    const int e0 = eg * 16;

    __shared__ float kvs[HD * HD];
    __shared__ float kss[HD];
    #pragma unroll
    for (int jj = 0; jj < 4; ++jj) {
        int flat = (jj * 256 + t) * 4;
        *(float4*)&kvs[flat] = *(const float4*)(kv_f + (size_t)bh * HD * HD + flat);
    }
    if (t < 16) *(float4*)&kss[t * 4] = *(const float4*)(ks_f + bh * HD + t * 4);
    __syncthreads();

    const float* qbase = qkv + ((size_t)b * O1 + hh * HD) * NSP + n;
    float acc[16][4] = {};
    float den[4] = {};
    for (int d = 0; d < 64; ++d) {
        float4 q4 = *(const float4*)(qbase + (size_t)d * NSP);
        float qa[4] = {q4.x, q4.y, q4.z, q4.w};
        float ksd = kss[d];
        #pragma unroll
        for (int j = 0; j < 4; ++j) den[j] += qa[j] * ksd;
        #pragma unroll
        for (int e4 = 0; e4 < 4; ++e4) {
            float4 kvv = *(const float4*)&kvs[d * HD + e0 + e4 * 4];
            float kvf[4] = {kvv.x, kvv.y, kvv.z, kvv.w};
            #pragma unroll
            for (int l = 0; l < 4; ++l)
                #pragma unroll
                for (int j = 0; j < 4; ++j)
                    acc[e4 * 4 + l][j] += kvf[l] * qa[j];
        }
    }
    float rden[4];
    #pragma unroll
    for (int j = 0; j < 4; ++j) rden[j] = 1.f / (den[j] + 1e-6f);
    float* obase = qkv + ((size_t)b * O1 + CCH + hh * HD) * NSP + n;  // k region
    #pragma unroll
    for (int el = 0; el < 16; ++el) {
        float4 r = {acc[el][0] * rden[0], acc[el][1] * rden[1],
                    acc[el][2] * rden[2], acc[el][3] * rden[3]};
        *(float4*)(obase + (size_t)(e0 + el) * NSP) = r;
    }
}

// ---------------------------------------------------------------------------
// Kernel 6: proj GEMM + bias + residual.
__global__ __launch_bounds__(256) void proj_gemm(const float* __restrict__ attn,
                                                 const float* __restrict__ w,
                                                 const float* __restrict__ bias,
                                                 const float* __restrict__ x,
                                                 float* __restrict__ out) {
    const int n0 = blockIdx.x * 64;
    const int o0 = blockIdx.y * 64;
    const int b  = blockIdx.z;
    const int t  = threadIdx.x;
    const int tx = t % 16, ty = t / 16;

    __shared__ float As[16][68];
    __shared__ float Bs[16][64];
    float acc[4][4] = {};

    const float* ab = attn + (size_t)b * O1 * NSP + (size_t)CCH * NSP;  // attn in k region
    const int la_o = t / 4;
    const int la_c = (t % 4) * 4;
    const int lb_c = t / 16;
    const int lb_n = (t % 16) * 4;

    for (int k0 = 0; k0 < CCH; k0 += 16) {
        float4 a4 = *(const float4*)(w + (size_t)(o0 + la_o) * CCH + k0 + la_c);
        float4 b4 = *(const float4*)(ab + (size_t)(k0 + lb_c) * NSP + n0 + lb_n);
        __syncthreads();
        As[la_c + 0][la_o] = a4.x;
        As[la_c + 1][la_o] = a4.y;
        As[la_c + 2][la_o] = a4.z;
        As[la_c + 3][la_o] = a4.w;
        *(float4*)&Bs[lb_c][lb_n] = b4;
        __syncthreads();
        #pragma unroll
        for (int kk = 0; kk < 16; ++kk) {
            float4 af = *(const float4*)&As[kk][ty * 4];
            float4 bf = *(const float4*)&Bs[kk][tx * 4];
            float av[4] = {af.x, af.y, af.z, af.w};
            float bv[4] = {bf.x, bf.y, bf.z, bf.w};
            #pragma unroll
            for (int i = 0; i < 4; ++i)
                #pragma unroll
                for (int j = 0; j < 4; ++j)
                    acc[i][j] += av[i] * bv[j];
        }
    }
    #pragma unroll
    for (int i = 0; i < 4; ++i) {
        int o = o0 + ty * 4 + i;
        float bs = bias[o];
        float4 xr = *(const float4*)(x + ((size_t)b * CCH + o) * NSP + n0 + tx * 4);
        float4 r = {acc[i][0] + bs + xr.x, acc[i][1] + bs + xr.y,
                    acc[i][2] + bs + xr.z, acc[i][3] + bs + xr.w};
        *(float4*)(out + ((size_t)b * CCH + o) * NSP + n0 + tx * 4) = r;
    }
}

// ---------------------------------------------------------------------------
extern "C" void kernel_launch(void* const* d_in, const int* in_sizes, int n_in,
                              void* d_out, int out_size, void* d_ws, size_t ws_size,
                              hipStream_t stream) {
    const float* x      = (const float*)d_in[0];
    const float* gamma  = (const float*)d_in[1];
    const float* beta   = (const float*)d_in[2];
    const float* qkv_w  = (const float*)d_in[3];
    const float* qkv_b  = (const float*)d_in[4];
    const float* proj_w = (const float*)d_in[5];
    const float* proj_b = (const float*)d_in[6];
    float* out = (float*)d_out;

    // workspace layout (floats): ss | qkv | kv_part | ks_part | kv_f | ks_f
    float* ws      = (float*)d_ws;
    float* ss      = ws;                                    //      8192
    float* qkv     = ss + 8192;                             // 50331648
    float* kv_part = qkv + (size_t)BATCH * O1 * NSP;        //  2097152
    float* ks_part = kv_part + (size_t)NCHUNK * 64 * HD * HD; //   32768
    float* kv_f    = ks_part + NCHUNK * 64 * HD;            //   262144
    float* ks_f    = kv_f + 64 * HD * HD;                   //     4096

    gn_stats<<<BATCH * NGROUPS, 256, 0, stream>>>(x, gamma, beta, ss);
    qkv_gemm<<<dim3(NSP / 64, O1 / 64, BATCH), 256, 0, stream>>>(x, ss, qkv_w, qkv_b, qkv);
    kv_partial<<<dim3(NCHUNK, BATCH * NHEADS), 256, 0, stream>>>(qkv, kv_part, ks_part);
    kv_reduce<<<(64 * HD * HD + 64 * HD + 255) / 256, 256, 0, stream>>>(kv_part, ks_part, kv_f, ks_f);
    attn_kernel<<<dim3(NSP / 256, BATCH * NHEADS), 256, 0, stream>>>(qkv, kv_f, ks_f);
    proj_gemm<<<dim3(NSP / 64, CCH / 64, BATCH), 256, 0, stream>>>(qkv, proj_w, proj_b, x, out);
}

// Round 2
// 394.517 us; speedup vs baseline: 2.8678x; 2.8678x over previous
//
#include <hip/hip_runtime.h>
#include <math.h>

#define BATCH   8
#define CCH     512
#define NHEADS  8
#define HD      64
#define NGROUPS 32
#define CPG     16
#define NSP     4096      // H*W
#define O1      1536      // 3*C
#define NCHUNK  8

typedef __attribute__((ext_vector_type(8))) short      short8;
typedef __attribute__((ext_vector_type(8))) unsigned short ushort8;
typedef __attribute__((ext_vector_type(4))) float      float4v;

#define GLOAD_LDS16(g, s) __builtin_amdgcn_global_load_lds(                   \
    (const __attribute__((address_space(1))) void*)(g),                       \
    (__attribute__((address_space(3))) void*)(s), 16, 0, 0)

// ---------------------------------------------------------------------------
__device__ __forceinline__ float phi_act(float v) {   // elu(x)+1
    return v > 0.f ? v + 1.f : __expf(v);
}
__device__ __forceinline__ unsigned short f2bf(float f) {  // RNE fp32->bf16
    union { float f; unsigned int u; } c; c.f = f;
    unsigned int u = c.u;
    u += 0x7fffu + ((u >> 16) & 1u);
    return (unsigned short)(u >> 16);
}

// ---------------------------------------------------------------------------
// Kernel 1: GroupNorm statistics -> per-(b,c) scale/shift
__global__ __launch_bounds__(256) void gn_stats(const float* __restrict__ x,
                                                const float* __restrict__ gamma,
                                                const float* __restrict__ beta,
                                                float* __restrict__ ss) {
    const int bg = blockIdx.x;
    const int t  = threadIdx.x;
    const float* base = x + (size_t)bg * (CPG * NSP);
    float s = 0.f, s2 = 0.f;
    #pragma unroll 4
    for (int i = 0; i < 64; ++i) {
        float4 v = *(const float4*)(base + (i * 256 + t) * 4);
        s  += v.x + v.y + v.z + v.w;
        s2 += v.x * v.x + v.y * v.y + v.z * v.z + v.w * v.w;
    }
    __shared__ float r1[256], r2[256];
    r1[t] = s; r2[t] = s2;
    __syncthreads();
    for (int off = 128; off > 0; off >>= 1) {
        if (t < off) { r1[t] += r1[t + off]; r2[t] += r2[t + off]; }
        __syncthreads();
    }
    if (t < CPG) {
        const float inv = 1.f / 65536.f;
        float mean = r1[0] * inv;
        float var  = r2[0] * inv - mean * mean;
        float rstd = rsqrtf(var + 1e-5f);
        int b = bg / NGROUPS, g = bg % NGROUPS;
        int c = g * CPG + t;
        float sc = gamma[c] * rstd;
        float sh = beta[c] - mean * sc;
        ss[(b * CCH + c) * 2]     = sc;
        ss[(b * CCH + c) * 2 + 1] = sh;
    }
}

// ---------------------------------------------------------------------------
// Kernel 2: weights fp32 -> bf16 (qkv_w 1536x512, proj_w 512x512)
__global__ __launch_bounds__(256) void conv_w(const float* __restrict__ qw,
                                              const float* __restrict__ pw,
                                              unsigned short* __restrict__ qwb,
                                              unsigned short* __restrict__ pwb) {
    int i = (blockIdx.x * 256 + threadIdx.x) * 4;
    if (i < O1 * CCH) {
        float4 v = *(const float4*)(qw + i);
        unsigned short o[4] = {f2bf(v.x), f2bf(v.y), f2bf(v.z), f2bf(v.w)};
        *(uint2*)(qwb + i) = *(uint2*)o;
    } else {
        int j = i - O1 * CCH;
        float4 v = *(const float4*)(pw + j);
        unsigned short o[4] = {f2bf(v.x), f2bf(v.y), f2bf(v.z), f2bf(v.w)};
        *(uint2*)(pwb + j) = *(uint2*)o;
    }
}

// ---------------------------------------------------------------------------
// Kernel 3: xnT[b][n][c] bf16 = GroupNorm(x)[b][c][n] transposed.
// 64x64 LDS tile transpose per block.
__global__ __launch_bounds__(256) void xnT_kernel(const float* __restrict__ x,
                                                  const float* __restrict__ ss,
                                                  unsigned short* __restrict__ xnT) {
    const int n0 = blockIdx.x * 64, c0 = blockIdx.y * 64, b = blockIdx.z;
    const int t = threadIdx.x;
    __shared__ float tile[64][65];
    const float* xb  = x + ((size_t)b * CCH + c0) * NSP + n0;
    const float* ssb = ss + b * CCH * 2;

    const int lr = t / 16, lc = (t % 16) * 4;
    #pragma unroll
    for (int j = 0; j < 4; ++j) {
        int cr = j * 16 + lr;
        float4 v = *(const float4*)(xb + (size_t)cr * NSP + lc);
        float sc = ssb[(c0 + cr) * 2], sh = ssb[(c0 + cr) * 2 + 1];
        tile[cr][lc + 0] = v.x * sc + sh;
        tile[cr][lc + 1] = v.y * sc + sh;
        tile[cr][lc + 2] = v.z * sc + sh;
        tile[cr][lc + 3] = v.w * sc + sh;
    }
    __syncthreads();
    #pragma unroll
    for (int j = 0; j < 2; ++j) {
        int wd = j * 256 + t;
        int n  = wd >> 3;
        int cb = (wd & 7) * 8;
        ushort8 o;
        #pragma unroll
        for (int i = 0; i < 8; ++i) o[i] = f2bf(tile[cb + i][n]);
        *(ushort8*)(xnT + ((size_t)b * NSP + n0 + n) * CCH + c0 + cb) = o;
    }
}

// ---------------------------------------------------------------------------
// Kernel 4/7: MFMA GEMM.  out[b,o,n] = sum_c A[o,c]*Bt[b,n,c] + bias[o]
// MODE 0: qkv (phi on o<1024), out stride O1.  MODE 1: proj (+resid), stride CCH.
// 128x128 tile, BK=32, 256 thr = 4 waves (2x2 of 64x64), mfma 16x16x32 bf16.
template<int MODE>
__global__ __launch_bounds__(256) void gemm_mfma(const unsigned short* __restrict__ A,
                                                 const unsigned short* __restrict__ BtBase,
                                                 size_t bStride,              // ushorts per batch
                                                 const float* __restrict__ bias,
                                                 const float* __restrict__ resid,
                                                 float* __restrict__ out,
                                                 int OCH) {
    const int n0 = blockIdx.x * 128;
    const int o0 = blockIdx.y * 128;
    const int b  = blockIdx.z;
    const int t  = threadIdx.x;
    const int wv = t >> 6, ln = t & 63;
    const int quad = ln >> 4, lm = ln & 15;
    const int wm = (wv >> 1) * 64, wn = (wv & 1) * 64;

    __shared__ __align__(16) unsigned short As[128 * 32];
    __shared__ __align__(16) unsigned short Bs[128 * 32];

    float4v acc[4][4];
    #pragma unroll
    for (int i = 0; i < 4; ++i)
        #pragma unroll
        for (int j = 0; j < 4; ++j) acc[i][j] = {0.f, 0.f, 0.f, 0.f};

    const unsigned short* aBase = A + (size_t)o0 * CCH;
    const unsigned short* bBase = BtBase + (size_t)b * bStride + (size_t)n0 * CCH;

    const int srow = ln >> 2;            // row within 16-row chunk
    const int scol = (ln & 3) * 8;       // bf16 offset within row's 64B slice

    for (int k0 = 0; k0 < CCH; k0 += 32) {
        __syncthreads();
        // stage A (8 KB) + B (8 KB): 4 chunks of 1KB per wave
        GLOAD_LDS16(aBase + (size_t)(wv * 16 + srow) * CCH + k0 + scol,
                    As + wv * 512);
        GLOAD_LDS16(aBase + (size_t)(64 + wv * 16 + srow) * CCH + k0 + scol,
                    As + 2048 + wv * 512);
        GLOAD_LDS16(bBase + (size_t)(wv * 16 + srow) * CCH + k0 + scol,
                    Bs + wv * 512);
        GLOAD_LDS16(bBase + (size_t)(64 + wv * 16 + srow) * CCH + k0 + scol,
                    Bs + 2048 + wv * 512);
        __syncthreads();

        short8 af[4], bf[4];
        #pragma unroll
        for (int i = 0; i < 4; ++i)
            af[i] = *(const short8*)(As + (wm + i * 16 + lm) * 32 + quad * 8);
        #pragma unroll
        for (int j = 0; j < 4; ++j)
            bf[j] = *(const short8*)(Bs + (wn + j * 16 + lm) * 32 + quad * 8);
        #pragma unroll
        for (int i = 0; i < 4; ++i)
            #pragma unroll
            for (int j = 0; j < 4; ++j)
                acc[i][j] = __builtin_amdgcn_mfma_f32_16x16x32_bf16(
                    af[i], bf[j], acc[i][j], 0, 0, 0);
    }

    // epilogue: C/D layout col=lm -> n, row=quad*4+r -> o
    #pragma unroll
    for (int i = 0; i < 4; ++i) {
        #pragma unroll
        for (int r = 0; r < 4; ++r) {
            int o = o0 + wm + i * 16 + quad * 4 + r;
            float bs = bias[o];
            #pragma unroll
            for (int j = 0; j < 4; ++j) {
                int n = n0 + wn + j * 16 + lm;
                float v = acc[i][j][r] + bs;
                if (MODE == 0) {
                    if (o < 2 * CCH) v = phi_act(v);
                } else {
                    v += resid[((size_t)b * CCH + o) * NSP + n];
                }
                out[((size_t)b * OCH + o) * NSP + n] = v;
            }
        }
    }
}

// ---------------------------------------------------------------------------
// Kernel 5: partial kv[d][e] = sum_n k[d][n]*v[e][n] and ksum[d], per n-chunk.
__global__ __launch_bounds__(256) void kv_partial(const float* __restrict__ qkv,
                                                  float* __restrict__ kv_part,
                                                  float* __restrict__ ks_part) {
    const int chunk = blockIdx.x;
    const int bh    = blockIdx.y;
    const int b = bh / NHEADS, hh = bh % NHEADS;
    const int t = threadIdx.x;
    const int d0 = (t / 16) * 4, e0 = (t % 16) * 4;

    __shared__ float kt[64 * 68];
    __shared__ float vt[64 * 68];

    const float* kbase = qkv + ((size_t)b * O1 + CCH     + hh * HD) * NSP;
    const float* vbase = qkv + ((size_t)b * O1 + 2 * CCH + hh * HD) * NSP;

    float acc[4][4] = {};
    float ks[4] = {};
    const int fl = t * 4;

    for (int nt = 0; nt < 8; ++nt) {
        int nbase = chunk * 512 + nt * 64;
        __syncthreads();
        #pragma unroll
        for (int j = 0; j < 4; ++j) {
            int flat = j * 1024 + fl;
            int dch = flat / 64, nl = flat % 64;
            float4 k4 = *(const float4*)(kbase + (size_t)dch * NSP + nbase + nl);
            float4 v4 = *(const float4*)(vbase + (size_t)dch * NSP + nbase + nl);
            *(float4*)&kt[dch * 68 + nl] = k4;
            *(float4*)&vt[dch * 68 + nl] = v4;
        }
        __syncthreads();
        for (int nl = 0; nl < 64; nl += 2) {
            float2 kf[4], vf[4];
            #pragma unroll
            for (int i = 0; i < 4; ++i) {
                kf[i] = *(const float2*)&kt[(d0 + i) * 68 + nl];
                vf[i] = *(const float2*)&vt[(e0 + i) * 68 + nl];
            }
            #pragma unroll
            for (int i = 0; i < 4; ++i)
                #pragma unroll
                for (int j = 0; j < 4; ++j)
                    acc[i][j] += kf[i].x * vf[j].x + kf[i].y * vf[j].y;
            if ((t % 16) == 0) {
                #pragma unroll
                for (int i = 0; i < 4; ++i) ks[i] += kf[i].x + kf[i].y;
            }
        }
    }
    float* kvp = kv_part + ((size_t)(chunk * 64 + bh)) * HD * HD;
    #pragma unroll
    for (int i = 0; i < 4; ++i) {
        float4 r = {acc[i][0], acc[i][1], acc[i][2], acc[i][3]};
        *(float4*)(kvp + (d0 + i) * HD + e0) = r;
    }
    if ((t % 16) == 0) {
        float4 r = {ks[0], ks[1], ks[2], ks[3]};
        *(float4*)(ks_part + ((size_t)(chunk * 64 + bh)) * HD + d0) = r;
    }
}

// ---------------------------------------------------------------------------
// Kernel 6: reduce the NCHUNK partials.
__global__ __launch_bounds__(256) void kv_reduce(const float* __restrict__ kv_part,
                                                 const float* __restrict__ ks_part,
                                                 float* __restrict__ kv_f,
                                                 float* __restrict__ ks_f) {
    const int idx = blockIdx.x * 256 + threadIdx.x;
    const int NKV = 64 * HD * HD;
    if (idx < NKV) {
        float s = 0.f;
        #pragma unroll
        for (int p = 0; p < NCHUNK; ++p) s += kv_part[(size_t)p * NKV + idx];
        kv_f[idx] = s;
    } else if (idx - NKV < 64 * HD) {
        int i2 = idx - NKV;
        float s = 0.f;
        #pragma unroll
        for (int p = 0; p < NCHUNK; ++p) s += ks_part[p * 64 * HD + i2];
        ks_f[i2] = s;
    }
}

// ---------------------------------------------------------------------------
// Kernel 7: out[n][e] = (sum_d q[d][n]*kv[d][e]) / (sum_d q[d][n]*ksum[d]+eps)
// Writes attnT[b][n][c] bf16 into the (dead) k region of qkv.
__global__ __launch_bounds__(256) void attn_kernel(float* __restrict__ qkv,
                                                   const float* __restrict__ kv_f,
                                                   const float* __restrict__ ks_f) {
    const int nblk = blockIdx.x;
    const int bh   = blockIdx.y;
    const int b = bh / NHEADS, hh = bh % NHEADS;
    const int t = threadIdx.x;
    const int tx = t % 64, eg = t / 64;
    const int n  = nblk * 256 + tx * 4;
    const int e0 = eg * 16;

    __shared__ float kvs[HD * HD];
    __shared__ float kss[HD];
    #pragma unroll
    for (int jj = 0; jj < 4; ++jj) {
        int flat = (jj * 256 + t) * 4;
        *(float4*)&kvs[flat] = *(const float4*)(kv_f + (size_t)bh * HD * HD + flat);
    }
    if (t < 16) *(float4*)&kss[t * 4] = *(const float4*)(ks_f + bh * HD + t * 4);
    __syncthreads();

    const float* qbase = qkv + ((size_t)b * O1 + hh * HD) * NSP + n;
    float acc[16][4] = {};
    float den[4] = {};
    for (int d = 0; d < 64; ++d) {
        float4 q4 = *(const float4*)(qbase + (size_t)d * NSP);
        float qa[4] = {q4.x, q4.y, q4.z, q4.w};
        float ksd = kss[d];
        #pragma unroll
        for (int j = 0; j < 4; ++j) den[j] += qa[j] * ksd;
        #pragma unroll
        for (int e4 = 0; e4 < 4; ++e4) {
            float4 kvv = *(const float4*)&kvs[d * HD + e0 + e4 * 4];
            float kvf[4] = {kvv.x, kvv.y, kvv.z, kvv.w};
            #pragma unroll
            for (int l = 0; l < 4; ++l)
                #pragma unroll
                for (int j = 0; j < 4; ++j)
                    acc[e4 * 4 + l][j] += kvf[l] * qa[j];
        }
    }
    float rden[4];
    #pragma unroll
    for (int j = 0; j < 4; ++j) rden[j] = 1.f / (den[j] + 1e-6f);

    // attnT bf16 [n][c], c = hh*64 + e0 + el, into k region of this batch
    unsigned short* aT = (unsigned short*)(qkv + ((size_t)b * O1 + CCH) * NSP);
    #pragma unroll
    for (int jn = 0; jn < 4; ++jn) {
        ushort8 w0, w1;
        #pragma unroll
        for (int l = 0; l < 8; ++l) w0[l] = f2bf(acc[l][jn] * rden[jn]);
        #pragma unroll
        for (int l = 0; l < 8; ++l) w1[l] = f2bf(acc[8 + l][jn] * rden[jn]);
        size_t off = ((size_t)(n + jn)) * CCH + hh * HD + e0;
        *(ushort8*)(aT + off)     = w0;
        *(ushort8*)(aT + off + 8) = w1;
    }
}

// ---------------------------------------------------------------------------
extern "C" void kernel_launch(void* const* d_in, const int* in_sizes, int n_in,
                              void* d_out, int out_size, void* d_ws, size_t ws_size,
                              hipStream_t stream) {
    const float* x      = (const float*)d_in[0];
    const float* gamma  = (const float*)d_in[1];
    const float* beta   = (const float*)d_in[2];
    const float* qkv_w  = (const float*)d_in[3];
    const float* qkv_b  = (const float*)d_in[4];
    const float* proj_w = (const float*)d_in[5];
    const float* proj_b = (const float*)d_in[6];
    float* out = (float*)d_out;

    // workspace (floats): ss | qkv | kv_part | ks_part | kv_f | ks_f | xnT | wq | wp
    float* ws      = (float*)d_ws;
    float* ss      = ws;
    float* qkv     = ss + 8192;
    float* kv_part = qkv + (size_t)BATCH * O1 * NSP;
    float* ks_part = kv_part + (size_t)NCHUNK * 64 * HD * HD;
    float* kv_f    = ks_part + NCHUNK * 64 * HD;
    float* ks_f    = kv_f + 64 * HD * HD;
    unsigned short* xnT = (unsigned short*)(ks_f + 64 * HD);
    unsigned short* wqb = xnT + (size_t)BATCH * NSP * CCH;
    unsigned short* wpb = wqb + (size_t)O1 * CCH;

    gn_stats<<<BATCH * NGROUPS, 256, 0, stream>>>(x, gamma, beta, ss);
    conv_w<<<(O1 * CCH + CCH * CCH) / 4 / 256, 256, 0, stream>>>(qkv_w, proj_w, wqb, wpb);
    xnT_kernel<<<dim3(NSP / 64, CCH / 64, BATCH), 256, 0, stream>>>(x, ss, xnT);

    gemm_mfma<0><<<dim3(NSP / 128, O1 / 128, BATCH), 256, 0, stream>>>(
        wqb, xnT, (size_t)NSP * CCH, qkv_b, nullptr, qkv, O1);

    kv_partial<<<dim3(NCHUNK, BATCH * NHEADS), 256, 0, stream>>>(qkv, kv_part, ks_part);
    kv_reduce<<<(64 * HD * HD + 64 * HD + 255) / 256, 256, 0, stream>>>(kv_part, ks_part, kv_f, ks_f);
    attn_kernel<<<dim3(NSP / 256, BATCH * NHEADS), 256, 0, stream>>>(qkv, kv_f, ks_f);

    // proj: B^T = attnT (bf16) living in the k region; per-batch stride O1*NSP floats
    const unsigned short* attnT = (const unsigned short*)(qkv + (size_t)CCH * NSP);
    gemm_mfma<1><<<dim3(NSP / 128, CCH / 128, BATCH), 256, 0, stream>>>(
        wpb, attnT, (size_t)O1 * NSP * 2, proj_b, x, out, CCH);
}

// Round 3
// 312.733 us; speedup vs baseline: 3.6178x; 1.2615x over previous
//
#include <hip/hip_runtime.h>
#include <math.h>

#define BATCH   8
#define CCH     512
#define NHEADS  8
#define HD      64
#define NGROUPS 32
#define CPG     16
#define NSP     4096      // H*W
#define O1      1536      // 3*C

typedef __attribute__((ext_vector_type(8))) short          short8;
typedef __attribute__((ext_vector_type(8))) unsigned short ushort8;
typedef __attribute__((ext_vector_type(4))) unsigned short ushort4v;
typedef __attribute__((ext_vector_type(4))) float          float4v;

#define GLOAD_LDS16(g, s) __builtin_amdgcn_global_load_lds(                   \
    (const __attribute__((address_space(1))) void*)(g),                       \
    (__attribute__((address_space(3))) void*)(s), 16, 0, 0)

// ---------------------------------------------------------------------------
__device__ __forceinline__ float phi_act(float v) {   // elu(x)+1
    return v > 0.f ? v + 1.f : __expf(v);
}
__device__ __forceinline__ unsigned short f2bf(float f) {  // RNE fp32->bf16
    union { float f; unsigned int u; } c; c.f = f;
    unsigned int u = c.u;
    u += 0x7fffu + ((u >> 16) & 1u);
    return (unsigned short)(u >> 16);
}
__device__ __forceinline__ float bf2f(unsigned short s) {
    union { unsigned int u; float f; } c; c.u = ((unsigned int)s) << 16;
    return c.f;
}

// ---------------------------------------------------------------------------
// Kernel 1: GroupNorm statistics -> per-(b,c) scale/shift
__global__ __launch_bounds__(256) void gn_stats(const float* __restrict__ x,
                                                const float* __restrict__ gamma,
                                                const float* __restrict__ beta,
                                                float* __restrict__ ss) {
    const int bg = blockIdx.x;
    const int t  = threadIdx.x;
    const float* base = x + (size_t)bg * (CPG * NSP);
    float s = 0.f, s2 = 0.f;
    #pragma unroll 4
    for (int i = 0; i < 64; ++i) {
        float4 v = *(const float4*)(base + (i * 256 + t) * 4);
        s  += v.x + v.y + v.z + v.w;
        s2 += v.x * v.x + v.y * v.y + v.z * v.z + v.w * v.w;
    }
    __shared__ float r1[256], r2[256];
    r1[t] = s; r2[t] = s2;
    __syncthreads();
    for (int off = 128; off > 0; off >>= 1) {
        if (t < off) { r1[t] += r1[t + off]; r2[t] += r2[t + off]; }
        __syncthreads();
    }
    if (t < CPG) {
        const float inv = 1.f / 65536.f;
        float mean = r1[0] * inv;
        float var  = r2[0] * inv - mean * mean;
        float rstd = rsqrtf(var + 1e-5f);
        int b = bg / NGROUPS, g = bg % NGROUPS;
        int c = g * CPG + t;
        float sc = gamma[c] * rstd;
        float sh = beta[c] - mean * sc;
        ss[(b * CCH + c) * 2]     = sc;
        ss[(b * CCH + c) * 2 + 1] = sh;
    }
}

// ---------------------------------------------------------------------------
// Kernel 2: weights fp32 -> bf16; block 0 also zeroes ksum (atomic target).
__global__ __launch_bounds__(256) void conv_w(const float* __restrict__ qw,
                                              const float* __restrict__ pw,
                                              unsigned short* __restrict__ qwb,
                                              unsigned short* __restrict__ pwb,
                                              float* __restrict__ ksum) {
    int i = (blockIdx.x * 256 + threadIdx.x) * 4;
    if (i < O1 * CCH) {
        float4 v = *(const float4*)(qw + i);
        unsigned short o[4] = {f2bf(v.x), f2bf(v.y), f2bf(v.z), f2bf(v.w)};
        *(uint2*)(qwb + i) = *(uint2*)o;
    } else {
        int j = i - O1 * CCH;
        float4 v = *(const float4*)(pw + j);
        unsigned short o[4] = {f2bf(v.x), f2bf(v.y), f2bf(v.z), f2bf(v.w)};
        *(uint2*)(pwb + j) = *(uint2*)o;
    }
    if (blockIdx.x == 0) {
        float4 z = {0.f, 0.f, 0.f, 0.f};
        #pragma unroll
        for (int l = 0; l < 4; ++l)
            *(float4*)(ksum + (l * 256 + threadIdx.x) * 4) = z;
    }
}

// ---------------------------------------------------------------------------
// Kernel 3: xnT[b][n][c] bf16 = GroupNorm(x)[b][c][n] transposed.
__global__ __launch_bounds__(256) void xnT_kernel(const float* __restrict__ x,
                                                  const float* __restrict__ ss,
                                                  unsigned short* __restrict__ xnT) {
    const int n0 = blockIdx.x * 64, c0 = blockIdx.y * 64, b = blockIdx.z;
    const int t = threadIdx.x;
    __shared__ float tile[64][65];
    const float* xb  = x + ((size_t)b * CCH + c0) * NSP + n0;
    const float* ssb = ss + b * CCH * 2;

    const int lr = t / 16, lc = (t % 16) * 4;
    #pragma unroll
    for (int j = 0; j < 4; ++j) {
        int cr = j * 16 + lr;
        float4 v = *(const float4*)(xb + (size_t)cr * NSP + lc);
        float sc = ssb[(c0 + cr) * 2], sh = ssb[(c0 + cr) * 2 + 1];
        tile[cr][lc + 0] = v.x * sc + sh;
        tile[cr][lc + 1] = v.y * sc + sh;
        tile[cr][lc + 2] = v.z * sc + sh;
        tile[cr][lc + 3] = v.w * sc + sh;
    }
    __syncthreads();
    #pragma unroll
    for (int j = 0; j < 2; ++j) {
        int wd = j * 256 + t;
        int n  = wd >> 3;
        int cb = (wd & 7) * 8;
        ushort8 o;
        #pragma unroll
        for (int i = 0; i < 8; ++i) o[i] = f2bf(tile[cb + i][n]);
        *(ushort8*)(xnT + ((size_t)b * NSP + n0 + n) * CCH + c0 + cb) = o;
    }
}

// ---------------------------------------------------------------------------
// Kernel 4/8: MFMA GEMM over o-tile[128] x n-tile[128], K=512, BK=32.
// MODE 0 (qkv): q blocks (o0<512): mfma(w,x) -> rows=o, phi, 8B stores to
//   qT[b][n][c]. k/v blocks: mfma(x,w) -> rows=n, 8B stores to kb/vb[b][c][n],
//   phi+ksum atomics for k.
// MODE 1 (proj): mfma(attnT,w) -> rows=n, float4 resid+bias epilogue to out.
template<int MODE>
__global__ __launch_bounds__(256) void gemm_mfma(const unsigned short* __restrict__ A,
                                                 const unsigned short* __restrict__ Bt,
                                                 size_t bStride,
                                                 const float* __restrict__ bias,
                                                 const float* __restrict__ resid,
                                                 float* __restrict__ outF,
                                                 unsigned short* __restrict__ qT,
                                                 unsigned short* __restrict__ kb,
                                                 unsigned short* __restrict__ vb,
                                                 float* __restrict__ ksum) {
    const int n0 = blockIdx.x * 128;
    const int o0 = blockIdx.y * 128;
    const int b  = blockIdx.z;
    const int t  = threadIdx.x;
    const int wv = t >> 6, ln = t & 63;
    const int quad = ln >> 4, lm = ln & 15;
    const int wo = (wv >> 1) * 64, wn = (wv & 1) * 64;

    __shared__ __align__(16) unsigned short As[128 * 32];
    __shared__ __align__(16) unsigned short Bs[128 * 32];

    float4v acc[4][4];
    #pragma unroll
    for (int i = 0; i < 4; ++i)
        #pragma unroll
        for (int j = 0; j < 4; ++j) acc[i][j] = {0.f, 0.f, 0.f, 0.f};

    const unsigned short* aBase = A + (size_t)o0 * CCH;
    const unsigned short* bBase = Bt + (size_t)b * bStride + (size_t)n0 * CCH;

    const int srow = ln >> 2;
    const int scol = (ln & 3) * 8;
    const bool kvori = (MODE == 1) || (o0 >= 512);

    for (int k0 = 0; k0 < CCH; k0 += 32) {
        __syncthreads();
        GLOAD_LDS16(aBase + (size_t)(wv * 16 + srow) * CCH + k0 + scol,
                    As + wv * 512);
        GLOAD_LDS16(aBase + (size_t)(64 + wv * 16 + srow) * CCH + k0 + scol,
                    As + 2048 + wv * 512);
        GLOAD_LDS16(bBase + (size_t)(wv * 16 + srow) * CCH + k0 + scol,
                    Bs + wv * 512);
        GLOAD_LDS16(bBase + (size_t)(64 + wv * 16 + srow) * CCH + k0 + scol,
                    Bs + 2048 + wv * 512);
        __syncthreads();

        short8 fw[4], fx[4];
        #pragma unroll
        for (int i = 0; i < 4; ++i)
            fw[i] = *(const short8*)(As + (wo + i * 16 + lm) * 32 + quad * 8);
        #pragma unroll
        for (int j = 0; j < 4; ++j)
            fx[j] = *(const short8*)(Bs + (wn + j * 16 + lm) * 32 + quad * 8);
        if (!kvori) {
            #pragma unroll
            for (int i = 0; i < 4; ++i)
                #pragma unroll
                for (int j = 0; j < 4; ++j)
                    acc[i][j] = __builtin_amdgcn_mfma_f32_16x16x32_bf16(
                        fw[i], fx[j], acc[i][j], 0, 0, 0);
        } else {
            #pragma unroll
            for (int i = 0; i < 4; ++i)
                #pragma unroll
                for (int j = 0; j < 4; ++j)
                    acc[i][j] = __builtin_amdgcn_mfma_f32_16x16x32_bf16(
                        fx[j], fw[i], acc[i][j], 0, 0, 0);
        }
    }

    if (MODE == 0) {
        if (o0 < 512) {
            // q: rows=o (quad*4+r), cols=n (lm). phi, store 4 consecutive o.
            #pragma unroll
            for (int i = 0; i < 4; ++i) {
                int ob = o0 + wo + i * 16 + quad * 4;
                float4 b4 = *(const float4*)(bias + ob);
                float bs[4] = {b4.x, b4.y, b4.z, b4.w};
                #pragma unroll
                for (int j = 0; j < 4; ++j) {
                    int n = n0 + wn + j * 16 + lm;
                    ushort4v pk;
                    #pragma unroll
                    for (int r = 0; r < 4; ++r)
                        pk[r] = f2bf(phi_act(acc[i][j][r] + bs[r]));
                    *(ushort4v*)(qT + ((size_t)b * NSP + n) * CCH + ob) = pk;
                }
            }
        } else {
            // k/v: rows=n (quad*4+r), cols=o (lm). store 4 consecutive n.
            const bool isk = (o0 < 1024);
            unsigned short* dst = isk ? kb : vb;
            const int cb0 = o0 - (isk ? 512 : 1024);
            #pragma unroll
            for (int i = 0; i < 4; ++i) {
                int o = o0 + wo + i * 16 + lm;
                int c = cb0 + wo + i * 16 + lm;
                float bs = bias[o];
                float ksp = 0.f;
                #pragma unroll
                for (int j = 0; j < 4; ++j) {
                    int n = n0 + wn + j * 16 + quad * 4;
                    ushort4v pk;
                    #pragma unroll
                    for (int r = 0; r < 4; ++r) {
                        float v = acc[i][j][r] + bs;
                        if (isk) { v = phi_act(v); ksp += v; }
                        pk[r] = f2bf(v);
                    }
                    *(ushort4v*)(dst + ((size_t)b * CCH + c) * NSP + n) = pk;
                }
                if (isk) {
                    ksp += __shfl_xor(ksp, 16);
                    ksp += __shfl_xor(ksp, 32);
                    if (quad == 0) atomicAdd(ksum + b * CCH + c, ksp);
                }
            }
        }
    } else {
        // proj: rows=n, cols=o. float4 bias+resid epilogue.
        #pragma unroll
        for (int i = 0; i < 4; ++i) {
            int o = o0 + wo + i * 16 + lm;
            float bs = bias[o];
            #pragma unroll
            for (int j = 0; j < 4; ++j) {
                int n = n0 + wn + j * 16 + quad * 4;
                size_t off = ((size_t)b * CCH + o) * NSP + n;
                float4 rv = *(const float4*)(resid + off);
                float4 w = {acc[i][j][0] + bs + rv.x, acc[i][j][1] + bs + rv.y,
                            acc[i][j][2] + bs + rv.z, acc[i][j][3] + bs + rv.w};
                *(float4*)(outF + off) = w;
            }
        }
    }
}

// ---------------------------------------------------------------------------
// Kernel 5: kv partials via MFMA. kv[d][e] = sum_n k[d][n]*v[e][n].
// grid (4 chunks, 64 bh). BK=64 staged as two 32-wide subtiles.
__global__ __launch_bounds__(256) void kv_mfma(const unsigned short* __restrict__ kb,
                                               const unsigned short* __restrict__ vb,
                                               float* __restrict__ kvp) {
    const int chunk = blockIdx.x, bh = blockIdx.y;
    const int b = bh >> 3, h = bh & 7;
    const int t = threadIdx.x;
    const int wv = t >> 6, ln = t & 63;
    const int quad = ln >> 4, lm = ln & 15;
    const int wd = (wv >> 1) * 32, we = (wv & 1) * 32;

    __shared__ __align__(16) unsigned short kt[2 * 64 * 32];  // [kk][d][32n]
    __shared__ __align__(16) unsigned short vt[2 * 64 * 32];

    float4v acc[2][2];
    #pragma unroll
    for (int i = 0; i < 2; ++i)
        #pragma unroll
        for (int j = 0; j < 2; ++j) acc[i][j] = {0.f, 0.f, 0.f, 0.f};

    const unsigned short* kbase = kb + ((size_t)b * CCH + h * 64) * NSP + chunk * 1024;
    const unsigned short* vbase = vb + ((size_t)b * CCH + h * 64) * NSP + chunk * 1024;
    const int srow = ln >> 2, scol = (ln & 3) * 8;

    for (int it = 0; it < 16; ++it) {
        int noff = it * 64;
        __syncthreads();
        GLOAD_LDS16(kbase + (size_t)(wv * 16 + srow) * NSP + noff + scol,      kt + wv * 512);
        GLOAD_LDS16(kbase + (size_t)(wv * 16 + srow) * NSP + noff + 32 + scol, kt + 2048 + wv * 512);
        GLOAD_LDS16(vbase + (size_t)(wv * 16 + srow) * NSP + noff + scol,      vt + wv * 512);
        GLOAD_LDS16(vbase + (size_t)(wv * 16 + srow) * NSP + noff + 32 + scol, vt + 2048 + wv * 512);
        __syncthreads();
        #pragma unroll
        for (int kk = 0; kk < 2; ++kk) {
            short8 a0 = *(const short8*)(kt + kk * 2048 + (wd + lm) * 32 + quad * 8);
            short8 a1 = *(const short8*)(kt + kk * 2048 + (wd + 16 + lm) * 32 + quad * 8);
            short8 b0 = *(const short8*)(vt + kk * 2048 + (we + lm) * 32 + quad * 8);
            short8 b1 = *(const short8*)(vt + kk * 2048 + (we + 16 + lm) * 32 + quad * 8);
            acc[0][0] = __builtin_amdgcn_mfma_f32_16x16x32_bf16(a0, b0, acc[0][0], 0, 0, 0);
            acc[0][1] = __builtin_amdgcn_mfma_f32_16x16x32_bf16(a0, b1, acc[0][1], 0, 0, 0);
            acc[1][0] = __builtin_amdgcn_mfma_f32_16x16x32_bf16(a1, b0, acc[1][0], 0, 0, 0);
            acc[1][1] = __builtin_amdgcn_mfma_f32_16x16x32_bf16(a1, b1, acc[1][1], 0, 0, 0);
        }
    }
    // rows=d (quad*4+r), cols=e (lm) -> store [e][d], 4 consecutive d.
    #pragma unroll
    for (int i = 0; i < 2; ++i)
        #pragma unroll
        for (int j = 0; j < 2; ++j) {
            int e = we + j * 16 + lm;
            int d = wd + i * 16 + quad * 4;
            float4 r = {acc[i][j][0], acc[i][j][1], acc[i][j][2], acc[i][j][3]};
            *(float4*)(kvp + ((size_t)(chunk * 64 + bh) * 64 + e) * 64 + d) = r;
        }
}

// ---------------------------------------------------------------------------
// Kernel 6: reduce 4 chunk partials -> kvTb[bh][e][d] bf16.
__global__ __launch_bounds__(256) void kv_reduce(const float* __restrict__ kvp,
                                                 unsigned short* __restrict__ kvTb) {
    int idx4 = (blockIdx.x * 256 + threadIdx.x) * 4;   // over 64*64*64
    float4 s = {0.f, 0.f, 0.f, 0.f};
    #pragma unroll
    for (int p = 0; p < 4; ++p) {
        float4 v = *(const float4*)(kvp + (size_t)p * (64 * 64 * 64) + idx4);
        s.x += v.x; s.y += v.y; s.z += v.z; s.w += v.w;
    }
    ushort4v o = {f2bf(s.x), f2bf(s.y), f2bf(s.z), f2bf(s.w)};
    *(ushort4v*)(kvTb + idx4) = o;
}

// ---------------------------------------------------------------------------
// Kernel 7: attn via MFMA. out[n][e] = (sum_d qT[n][d]*kvT[e][d]) / den[n].
// A = kvT (LDS, stride-72 rows), B = qT fragments from global.
// grid (16 nblk, 64 bh), 4 waves x 64 n each.
__global__ __launch_bounds__(256) void attn_mfma(const unsigned short* __restrict__ qT,
                                                 const unsigned short* __restrict__ kvTb,
                                                 const float* __restrict__ ksum,
                                                 unsigned short* __restrict__ attnT) {
    const int n0 = blockIdx.x * 256;
    const int bh = blockIdx.y;
    const int b = bh >> 3, h = bh & 7;
    const int t = threadIdx.x;
    const int wv = t >> 6, ln = t & 63;
    const int quad = ln >> 4, lm = ln & 15;
    const int nb = n0 + wv * 64;

    __shared__ __align__(16) unsigned short kvs[64 * 72];
    __shared__ float kss[64];

    #pragma unroll
    for (int l = 0; l < 2; ++l) {
        int ch = l * 256 + t;            // 512 chunks of 8 ushorts
        int e = ch >> 3, c8 = ch & 7;
        *(ushort8*)(kvs + e * 72 + c8 * 8) =
            *(const ushort8*)(kvTb + (size_t)bh * 4096 + ch * 8);
    }
    if (t < 64) kss[t] = ksum[b * CCH + h * 64 + t];
    __syncthreads();

    short8 bq[4][2];
    #pragma unroll
    for (int j = 0; j < 4; ++j)
        #pragma unroll
        for (int kk = 0; kk < 2; ++kk) {
            int n = nb + j * 16 + lm;
            bq[j][kk] = *(const short8*)(qT + ((size_t)b * NSP + n) * CCH +
                                         h * 64 + kk * 32 + quad * 8);
        }
    short8 ak[4][2];
    #pragma unroll
    for (int i = 0; i < 4; ++i)
        #pragma unroll
        for (int kk = 0; kk < 2; ++kk)
            ak[i][kk] = *(const short8*)(kvs + (i * 16 + lm) * 72 + kk * 32 + quad * 8);

    float4v acc[4][4];
    #pragma unroll
    for (int i = 0; i < 4; ++i)
        #pragma unroll
        for (int j = 0; j < 4; ++j) acc[i][j] = {0.f, 0.f, 0.f, 0.f};
    #pragma unroll
    for (int kk = 0; kk < 2; ++kk)
        #pragma unroll
        for (int i = 0; i < 4; ++i)
            #pragma unroll
            for (int j = 0; j < 4; ++j)
                acc[i][j] = __builtin_amdgcn_mfma_f32_16x16x32_bf16(
                    ak[i][kk], bq[j][kk], acc[i][j], 0, 0, 0);

    // denominators: den[n=nb+j*16+lm] = sum_d q[n][d]*ksum[d]
    float rden[4];
    #pragma unroll
    for (int j = 0; j < 4; ++j) {
        float dp = 0.f;
        #pragma unroll
        for (int kk = 0; kk < 2; ++kk)
            #pragma unroll
            for (int l = 0; l < 8; ++l)
                dp += bf2f((unsigned short)bq[j][kk][l]) * kss[kk * 32 + quad * 8 + l];
        dp += __shfl_xor(dp, 16);
        dp += __shfl_xor(dp, 32);
        rden[j] = 1.f / (dp + 1e-6f);
    }

    // rows=e (quad*4+r), cols=n (lm): 4 consecutive e -> 8B store to attnT[n][c]
    #pragma unroll
    for (int i = 0; i < 4; ++i) {
        int e = i * 16 + quad * 4;
        #pragma unroll
        for (int j = 0; j < 4; ++j) {
            int n = nb + j * 16 + lm;
            ushort4v pk;
            #pragma unroll
            for (int r = 0; r < 4; ++r)
                pk[r] = f2bf(acc[i][j][r] * rden[j]);
            *(ushort4v*)(attnT + ((size_t)b * NSP + n) * CCH + h * 64 + e) = pk;
        }
    }
}

// ---------------------------------------------------------------------------
extern "C" void kernel_launch(void* const* d_in, const int* in_sizes, int n_in,
                              void* d_out, int out_size, void* d_ws, size_t ws_size,
                              hipStream_t stream) {
    const float* x      = (const float*)d_in[0];
    const float* gamma  = (const float*)d_in[1];
    const float* beta   = (const float*)d_in[2];
    const float* qkv_w  = (const float*)d_in[3];
    const float* qkv_b  = (const float*)d_in[4];
    const float* proj_w = (const float*)d_in[5];
    const float* proj_b = (const float*)d_in[6];
    float* out = (float*)d_out;

    // workspace layout (float units)
    float* ws   = (float*)d_ws;
    float* ss   = ws;                                   //    8192
    float* ksum = ss + 8192;                            //    4096
    float* kvp  = ksum + 4096;                          // 1048576
    unsigned short* xnT   = (unsigned short*)(kvp + 4 * 64 * 64 * 64);
    unsigned short* qT    = xnT + (size_t)BATCH * NSP * CCH;
    unsigned short* kb    = qT  + (size_t)BATCH * NSP * CCH;
    unsigned short* vb    = kb  + (size_t)BATCH * NSP * CCH;
    unsigned short* attnT = vb  + (size_t)BATCH * NSP * CCH;
    unsigned short* kvTb  = attnT + (size_t)BATCH * NSP * CCH;
    unsigned short* wqb   = kvTb + (size_t)64 * 64 * 64;
    unsigned short* wpb   = wqb + (size_t)O1 * CCH;

    gn_stats<<<BATCH * NGROUPS, 256, 0, stream>>>(x, gamma, beta, ss);
    conv_w<<<(O1 * CCH + CCH * CCH) / 4 / 256, 256, 0, stream>>>(qkv_w, proj_w, wqb, wpb, ksum);
    xnT_kernel<<<dim3(NSP / 64, CCH / 64, BATCH), 256, 0, stream>>>(x, ss, xnT);

    gemm_mfma<0><<<dim3(NSP / 128, O1 / 128, BATCH), 256, 0, stream>>>(
        wqb, xnT, (size_t)NSP * CCH, qkv_b, nullptr, nullptr, qT, kb, vb, ksum);

    kv_mfma<<<dim3(4, 64), 256, 0, stream>>>(kb, vb, kvp);
    kv_reduce<<<256, 256, 0, stream>>>(kvp, kvTb);
    attn_mfma<<<dim3(NSP / 256, 64), 256, 0, stream>>>(qT, kvTb, ksum, attnT);

    gemm_mfma<1><<<dim3(NSP / 128, CCH / 128, BATCH), 256, 0, stream>>>(
        wpb, attnT, (size_t)NSP * CCH, proj_b, x, out, nullptr, nullptr, nullptr, nullptr);
}

// Round 4
// 304.320 us; speedup vs baseline: 3.7178x; 1.0276x over previous
//
#include <hip/hip_runtime.h>
#include <math.h>

#define BATCH   8
#define CCH     512
#define NHEADS  8
#define HD      64
#define NGROUPS 32
#define CPG     16
#define NSP     4096      // H*W
#define O1      1536      // 3*C

typedef __attribute__((ext_vector_type(8))) short          short8;
typedef __attribute__((ext_vector_type(8))) unsigned short ushort8;
typedef __attribute__((ext_vector_type(4))) unsigned short ushort4v;
typedef __attribute__((ext_vector_type(4))) float          float4v;

#define GLOAD_LDS16(g, s) __builtin_amdgcn_global_load_lds(                   \
    (const __attribute__((address_space(1))) void*)(g),                       \
    (__attribute__((address_space(3))) void*)(s), 16, 0, 0)

// ---------------------------------------------------------------------------
__device__ __forceinline__ float phi_act(float v) {   // elu(x)+1
    return v > 0.f ? v + 1.f : __expf(v);
}
__device__ __forceinline__ unsigned short f2bf(float f) {  // RNE fp32->bf16
    union { float f; unsigned int u; } c; c.f = f;
    unsigned int u = c.u;
    u += 0x7fffu + ((u >> 16) & 1u);
    return (unsigned short)(u >> 16);
}
__device__ __forceinline__ float bf2f(unsigned short s) {
    union { unsigned int u; float f; } c; c.u = ((unsigned int)s) << 16;
    return c.f;
}

// LDS swizzle: 16B chunk c of row r stored at chunk position c ^ ((r>>1)&3).
// Staging lane ln (writes LDS chunk ln of a 1KB slab, row = slabrow0 + ln>>2,
// slabrow0 % 16 == 0) must therefore READ global chunk (ln&3)^((ln>>3)&3).
// Fragment read lane (quad,lm) reads chunk quad^((lm>>1)&3) of row base+lm.
// Result: conflict-free ds_read_b128 phases (8 lanes cover all 32 banks).

// ---------------------------------------------------------------------------
// Kernel 1: GroupNorm statistics -> per-(b,c) scale/shift
__global__ __launch_bounds__(256) void gn_stats(const float* __restrict__ x,
                                                const float* __restrict__ gamma,
                                                const float* __restrict__ beta,
                                                float* __restrict__ ss) {
    const int bg = blockIdx.x;
    const int t  = threadIdx.x;
    const float* base = x + (size_t)bg * (CPG * NSP);
    float s = 0.f, s2 = 0.f;
    #pragma unroll 4
    for (int i = 0; i < 64; ++i) {
        float4 v = *(const float4*)(base + (i * 256 + t) * 4);
        s  += v.x + v.y + v.z + v.w;
        s2 += v.x * v.x + v.y * v.y + v.z * v.z + v.w * v.w;
    }
    __shared__ float r1[256], r2[256];
    r1[t] = s; r2[t] = s2;
    __syncthreads();
    for (int off = 128; off > 0; off >>= 1) {
        if (t < off) { r1[t] += r1[t + off]; r2[t] += r2[t + off]; }
        __syncthreads();
    }
    if (t < CPG) {
        const float inv = 1.f / 65536.f;
        float mean = r1[0] * inv;
        float var  = r2[0] * inv - mean * mean;
        float rstd = rsqrtf(var + 1e-5f);
        int b = bg / NGROUPS, g = bg % NGROUPS;
        int c = g * CPG + t;
        float sc = gamma[c] * rstd;
        float sh = beta[c] - mean * sc;
        ss[(b * CCH + c) * 2]     = sc;
        ss[(b * CCH + c) * 2 + 1] = sh;
    }
}

// ---------------------------------------------------------------------------
// Kernel 2: weights fp32 -> bf16; block 0 also zeroes ksum (atomic target).
__global__ __launch_bounds__(256) void conv_w(const float* __restrict__ qw,
                                              const float* __restrict__ pw,
                                              unsigned short* __restrict__ qwb,
                                              unsigned short* __restrict__ pwb,
                                              float* __restrict__ ksum) {
    int i = (blockIdx.x * 256 + threadIdx.x) * 4;
    if (i < O1 * CCH) {
        float4 v = *(const float4*)(qw + i);
        unsigned short o[4] = {f2bf(v.x), f2bf(v.y), f2bf(v.z), f2bf(v.w)};
        *(uint2*)(qwb + i) = *(uint2*)o;
    } else {
        int j = i - O1 * CCH;
        float4 v = *(const float4*)(pw + j);
        unsigned short o[4] = {f2bf(v.x), f2bf(v.y), f2bf(v.z), f2bf(v.w)};
        *(uint2*)(pwb + j) = *(uint2*)o;
    }
    if (blockIdx.x == 0) {
        float4 z = {0.f, 0.f, 0.f, 0.f};
        #pragma unroll
        for (int l = 0; l < 4; ++l)
            *(float4*)(ksum + (l * 256 + threadIdx.x) * 4) = z;
    }
}

// ---------------------------------------------------------------------------
// Kernel 3: xnT[b][n][c] bf16 = GroupNorm(x)[b][c][n] transposed.
__global__ __launch_bounds__(256) void xnT_kernel(const float* __restrict__ x,
                                                  const float* __restrict__ ss,
                                                  unsigned short* __restrict__ xnT) {
    const int n0 = blockIdx.x * 64, c0 = blockIdx.y * 64, b = blockIdx.z;
    const int t = threadIdx.x;
    __shared__ float tile[64][65];
    const float* xb  = x + ((size_t)b * CCH + c0) * NSP + n0;
    const float* ssb = ss + b * CCH * 2;

    const int lr = t / 16, lc = (t % 16) * 4;
    #pragma unroll
    for (int j = 0; j < 4; ++j) {
        int cr = j * 16 + lr;
        float4 v = *(const float4*)(xb + (size_t)cr * NSP + lc);
        float sc = ssb[(c0 + cr) * 2], sh = ssb[(c0 + cr) * 2 + 1];
        tile[cr][lc + 0] = v.x * sc + sh;
        tile[cr][lc + 1] = v.y * sc + sh;
        tile[cr][lc + 2] = v.z * sc + sh;
        tile[cr][lc + 3] = v.w * sc + sh;
    }
    __syncthreads();
    #pragma unroll
    for (int j = 0; j < 2; ++j) {
        int wd = j * 256 + t;
        int n  = wd >> 3;
        int cb = (wd & 7) * 8;
        ushort8 o;
        #pragma unroll
        for (int i = 0; i < 8; ++i) o[i] = f2bf(tile[cb + i][n]);
        *(ushort8*)(xnT + ((size_t)b * NSP + n0 + n) * CCH + c0 + cb) = o;
    }
}

// ---------------------------------------------------------------------------
// Kernel 4: q GEMM. mfma(w, x) -> rows=o. phi, 8B stores to qT[b][n][c].
__global__ __launch_bounds__(256) void gemm_q(const unsigned short* __restrict__ A,
                                              const unsigned short* __restrict__ Bt,
                                              const float* __restrict__ bias,
                                              unsigned short* __restrict__ qT) {
    const int n0 = blockIdx.x * 128;
    const int o0 = blockIdx.y * 128;
    const int b  = blockIdx.z;
    const int t  = threadIdx.x;
    const int wv = t >> 6, ln = t & 63;
    const int quad = ln >> 4, lm = ln & 15;
    const int wo = (wv >> 1) * 64, wn = (wv & 1) * 64;

    __shared__ __align__(16) unsigned short As[128 * 32];
    __shared__ __align__(16) unsigned short Bs[128 * 32];

    float4v acc[4][4];
    #pragma unroll
    for (int i = 0; i < 4; ++i)
        #pragma unroll
        for (int j = 0; j < 4; ++j) acc[i][j] = {0.f, 0.f, 0.f, 0.f};

    const unsigned short* aBase = A + (size_t)o0 * CCH;
    const unsigned short* bBase = Bt + ((size_t)b * NSP + n0) * CCH;

    const int srow = ln >> 2;
    const int scs  = ((ln & 3) ^ ((ln >> 3) & 3)) * 8;   // staging inv-swizzle
    const int sc8  = (quad ^ ((lm >> 1) & 3)) * 8;       // fragment swizzle

    for (int k0 = 0; k0 < CCH; k0 += 32) {
        __syncthreads();
        GLOAD_LDS16(aBase + (size_t)(wv * 16 + srow) * CCH + k0 + scs,      As + wv * 512);
        GLOAD_LDS16(aBase + (size_t)(64 + wv * 16 + srow) * CCH + k0 + scs, As + 2048 + wv * 512);
        GLOAD_LDS16(bBase + (size_t)(wv * 16 + srow) * CCH + k0 + scs,      Bs + wv * 512);
        GLOAD_LDS16(bBase + (size_t)(64 + wv * 16 + srow) * CCH + k0 + scs, Bs + 2048 + wv * 512);
        __syncthreads();

        short8 fw[4], fx[4];
        #pragma unroll
        for (int i = 0; i < 4; ++i)
            fw[i] = *(const short8*)(As + (wo + i * 16 + lm) * 32 + sc8);
        #pragma unroll
        for (int j = 0; j < 4; ++j)
            fx[j] = *(const short8*)(Bs + (wn + j * 16 + lm) * 32 + sc8);
        #pragma unroll
        for (int i = 0; i < 4; ++i)
            #pragma unroll
            for (int j = 0; j < 4; ++j)
                acc[i][j] = __builtin_amdgcn_mfma_f32_16x16x32_bf16(
                    fw[i], fx[j], acc[i][j], 0, 0, 0);
    }

    // rows=o (quad*4+r), cols=n (lm). phi, store 4 consecutive o.
    #pragma unroll
    for (int i = 0; i < 4; ++i) {
        int ob = o0 + wo + i * 16 + quad * 4;
        float4 b4 = *(const float4*)(bias + ob);
        float bs[4] = {b4.x, b4.y, b4.z, b4.w};
        #pragma unroll
        for (int j = 0; j < 4; ++j) {
            int n = n0 + wn + j * 16 + lm;
            ushort4v pk;
            #pragma unroll
            for (int r = 0; r < 4; ++r)
                pk[r] = f2bf(phi_act(acc[i][j][r] + bs[r]));
            *(ushort4v*)(qT + ((size_t)b * NSP + n) * CCH + ob) = pk;
        }
    }
}

// ---------------------------------------------------------------------------
// Kernel 5: k/v GEMM. mfma(x, w) -> rows=n. 8B stores to kb/vb[b][c][n];
// phi + ksum atomics for k. grid.y: 0..3 -> k, 4..7 -> v.
__global__ __launch_bounds__(256) void gemm_kv(const unsigned short* __restrict__ A,
                                               const unsigned short* __restrict__ Bt,
                                               const float* __restrict__ bias,
                                               unsigned short* __restrict__ kb,
                                               unsigned short* __restrict__ vb,
                                               float* __restrict__ ksum) {
    const int n0 = blockIdx.x * 128;
    const int o0 = 512 + blockIdx.y * 128;
    const int b  = blockIdx.z;
    const int t  = threadIdx.x;
    const int wv = t >> 6, ln = t & 63;
    const int quad = ln >> 4, lm = ln & 15;
    const int wo = (wv >> 1) * 64, wn = (wv & 1) * 64;

    __shared__ __align__(16) unsigned short As[128 * 32];
    __shared__ __align__(16) unsigned short Bs[128 * 32];

    float4v acc[4][4];
    #pragma unroll
    for (int i = 0; i < 4; ++i)
        #pragma unroll
        for (int j = 0; j < 4; ++j) acc[i][j] = {0.f, 0.f, 0.f, 0.f};

    const unsigned short* aBase = A + (size_t)o0 * CCH;
    const unsigned short* bBase = Bt + ((size_t)b * NSP + n0) * CCH;

    const int srow = ln >> 2;
    const int scs  = ((ln & 3) ^ ((ln >> 3) & 3)) * 8;
    const int sc8  = (quad ^ ((lm >> 1) & 3)) * 8;

    for (int k0 = 0; k0 < CCH; k0 += 32) {
        __syncthreads();
        GLOAD_LDS16(aBase + (size_t)(wv * 16 + srow) * CCH + k0 + scs,      As + wv * 512);
        GLOAD_LDS16(aBase + (size_t)(64 + wv * 16 + srow) * CCH + k0 + scs, As + 2048 + wv * 512);
        GLOAD_LDS16(bBase + (size_t)(wv * 16 + srow) * CCH + k0 + scs,      Bs + wv * 512);
        GLOAD_LDS16(bBase + (size_t)(64 + wv * 16 + srow) * CCH + k0 + scs, Bs + 2048 + wv * 512);
        __syncthreads();

        short8 fw[4], fx[4];
        #pragma unroll
        for (int i = 0; i < 4; ++i)
            fw[i] = *(const short8*)(As + (wo + i * 16 + lm) * 32 + sc8);
        #pragma unroll
        for (int j = 0; j < 4; ++j)
            fx[j] = *(const short8*)(Bs + (wn + j * 16 + lm) * 32 + sc8);
        #pragma unroll
        for (int i = 0; i < 4; ++i)
            #pragma unroll
            for (int j = 0; j < 4; ++j)
                acc[i][j] = __builtin_amdgcn_mfma_f32_16x16x32_bf16(
                    fx[j], fw[i], acc[i][j], 0, 0, 0);
    }

    // rows=n (quad*4+r), cols=o (lm). store 4 consecutive n.
    const bool isk = (o0 < 1024);
    unsigned short* dst = isk ? kb : vb;
    const int cb0 = o0 - (isk ? 512 : 1024);
    #pragma unroll
    for (int i = 0; i < 4; ++i) {
        int o = o0 + wo + i * 16 + lm;
        int c = cb0 + wo + i * 16 + lm;
        float bs = bias[o];
        float ksp = 0.f;
        #pragma unroll
        for (int j = 0; j < 4; ++j) {
            int n = n0 + wn + j * 16 + quad * 4;
            ushort4v pk;
            #pragma unroll
            for (int r = 0; r < 4; ++r) {
                float v = acc[i][j][r] + bs;
                if (isk) { v = phi_act(v); ksp += v; }
                pk[r] = f2bf(v);
            }
            *(ushort4v*)(dst + ((size_t)b * CCH + c) * NSP + n) = pk;
        }
        if (isk) {
            ksp += __shfl_xor(ksp, 16);
            ksp += __shfl_xor(ksp, 32);
            if (quad == 0) atomicAdd(ksum + b * CCH + c, ksp);
        }
    }
}

// ---------------------------------------------------------------------------
// Kernel 6: kv partials via MFMA. kv[d][e] = sum_n k[d][n]*v[e][n].
__global__ __launch_bounds__(256) void kv_mfma(const unsigned short* __restrict__ kb,
                                               const unsigned short* __restrict__ vb,
                                               float* __restrict__ kvp) {
    const int chunk = blockIdx.x, bh = blockIdx.y;
    const int b = bh >> 3, h = bh & 7;
    const int t = threadIdx.x;
    const int wv = t >> 6, ln = t & 63;
    const int quad = ln >> 4, lm = ln & 15;
    const int wd = (wv >> 1) * 32, we = (wv & 1) * 32;

    __shared__ __align__(16) unsigned short kt[2 * 64 * 32];  // [kk][d][32n]
    __shared__ __align__(16) unsigned short vt[2 * 64 * 32];

    float4v acc[2][2];
    #pragma unroll
    for (int i = 0; i < 2; ++i)
        #pragma unroll
        for (int j = 0; j < 2; ++j) acc[i][j] = {0.f, 0.f, 0.f, 0.f};

    const unsigned short* kbase = kb + ((size_t)b * CCH + h * 64) * NSP + chunk * 1024;
    const unsigned short* vbase = vb + ((size_t)b * CCH + h * 64) * NSP + chunk * 1024;
    const int srow = ln >> 2;
    const int scs  = ((ln & 3) ^ ((ln >> 3) & 3)) * 8;
    const int sc8  = (quad ^ ((lm >> 1) & 3)) * 8;

    for (int it = 0; it < 16; ++it) {
        int noff = it * 64;
        __syncthreads();
        GLOAD_LDS16(kbase + (size_t)(wv * 16 + srow) * NSP + noff + scs,      kt + wv * 512);
        GLOAD_LDS16(kbase + (size_t)(wv * 16 + srow) * NSP + noff + 32 + scs, kt + 2048 + wv * 512);
        GLOAD_LDS16(vbase + (size_t)(wv * 16 + srow) * NSP + noff + scs,      vt + wv * 512);
        GLOAD_LDS16(vbase + (size_t)(wv * 16 + srow) * NSP + noff + 32 + scs, vt + 2048 + wv * 512);
        __syncthreads();
        #pragma unroll
        for (int kk = 0; kk < 2; ++kk) {
            short8 a0 = *(const short8*)(kt + kk * 2048 + (wd + lm) * 32 + sc8);
            short8 a1 = *(const short8*)(kt + kk * 2048 + (wd + 16 + lm) * 32 + sc8);
            short8 b0 = *(const short8*)(vt + kk * 2048 + (we + lm) * 32 + sc8);
            short8 b1 = *(const short8*)(vt + kk * 2048 + (we + 16 + lm) * 32 + sc8);
            acc[0][0] = __builtin_amdgcn_mfma_f32_16x16x32_bf16(a0, b0, acc[0][0], 0, 0, 0);
            acc[0][1] = __builtin_amdgcn_mfma_f32_16x16x32_bf16(a0, b1, acc[0][1], 0, 0, 0);
            acc[1][0] = __builtin_amdgcn_mfma_f32_16x16x32_bf16(a1, b0, acc[1][0], 0, 0, 0);
            acc[1][1] = __builtin_amdgcn_mfma_f32_16x16x32_bf16(a1, b1, acc[1][1], 0, 0, 0);
        }
    }
    // rows=d (quad*4+r), cols=e (lm) -> store [e][d], 4 consecutive d.
    #pragma unroll
    for (int i = 0; i < 2; ++i)
        #pragma unroll
        for (int j = 0; j < 2; ++j) {
            int e = we + j * 16 + lm;
            int d = wd + i * 16 + quad * 4;
            float4 r = {acc[i][j][0], acc[i][j][1], acc[i][j][2], acc[i][j][3]};
            *(float4*)(kvp + ((size_t)(chunk * 64 + bh) * 64 + e) * 64 + d) = r;
        }
}

// ---------------------------------------------------------------------------
// Kernel 7: reduce 4 chunk partials -> kvTb[bh][e][d] bf16.
__global__ __launch_bounds__(256) void kv_reduce(const float* __restrict__ kvp,
                                                 unsigned short* __restrict__ kvTb) {
    int idx4 = (blockIdx.x * 256 + threadIdx.x) * 4;   // over 64*64*64
    float4 s = {0.f, 0.f, 0.f, 0.f};
    #pragma unroll
    for (int p = 0; p < 4; ++p) {
        float4 v = *(const float4*)(kvp + (size_t)p * (64 * 64 * 64) + idx4);
        s.x += v.x; s.y += v.y; s.z += v.z; s.w += v.w;
    }
    ushort4v o = {f2bf(s.x), f2bf(s.y), f2bf(s.z), f2bf(s.w)};
    *(ushort4v*)(kvTb + idx4) = o;
}

// ---------------------------------------------------------------------------
// Kernel 8: attn via MFMA. out[n][e] = (sum_d qT[n][d]*kvT[e][d]) / den[n].
__global__ __launch_bounds__(256) void attn_mfma(const unsigned short* __restrict__ qT,
                                                 const unsigned short* __restrict__ kvTb,
                                                 const float* __restrict__ ksum,
                                                 unsigned short* __restrict__ attnT) {
    const int n0 = blockIdx.x * 256;
    const int bh = blockIdx.y;
    const int b = bh >> 3, h = bh & 7;
    const int t = threadIdx.x;
    const int wv = t >> 6, ln = t & 63;
    const int quad = ln >> 4, lm = ln & 15;
    const int nb = n0 + wv * 64;

    __shared__ __align__(16) unsigned short kvs[64 * 72];
    __shared__ float kss[64];

    #pragma unroll
    for (int l = 0; l < 2; ++l) {
        int ch = l * 256 + t;            // 512 chunks of 8 ushorts
        int e = ch >> 3, c8 = ch & 7;
        *(ushort8*)(kvs + e * 72 + c8 * 8) =
            *(const ushort8*)(kvTb + (size_t)bh * 4096 + ch * 8);
    }
    if (t < 64) kss[t] = ksum[b * CCH + h * 64 + t];
    __syncthreads();

    short8 bq[4][2];
    #pragma unroll
    for (int j = 0; j < 4; ++j)
        #pragma unroll
        for (int kk = 0; kk < 2; ++kk) {
            int n = nb + j * 16 + lm;
            bq[j][kk] = *(const short8*)(qT + ((size_t)b * NSP + n) * CCH +
                                         h * 64 + kk * 32 + quad * 8);
        }
    short8 ak[4][2];
    #pragma unroll
    for (int i = 0; i < 4; ++i)
        #pragma unroll
        for (int kk = 0; kk < 2; ++kk)
            ak[i][kk] = *(const short8*)(kvs + (i * 16 + lm) * 72 + kk * 32 + quad * 8);

    float4v acc[4][4];
    #pragma unroll
    for (int i = 0; i < 4; ++i)
        #pragma unroll
        for (int j = 0; j < 4; ++j) acc[i][j] = {0.f, 0.f, 0.f, 0.f};
    #pragma unroll
    for (int kk = 0; kk < 2; ++kk)
        #pragma unroll
        for (int i = 0; i < 4; ++i)
            #pragma unroll
            for (int j = 0; j < 4; ++j)
                acc[i][j] = __builtin_amdgcn_mfma_f32_16x16x32_bf16(
                    ak[i][kk], bq[j][kk], acc[i][j], 0, 0, 0);

    // denominators: den[n=nb+j*16+lm] = sum_d q[n][d]*ksum[d]
    float rden[4];
    #pragma unroll
    for (int j = 0; j < 4; ++j) {
        float dp = 0.f;
        #pragma unroll
        for (int kk = 0; kk < 2; ++kk)
            #pragma unroll
            for (int l = 0; l < 8; ++l)
                dp += bf2f((unsigned short)bq[j][kk][l]) * kss[kk * 32 + quad * 8 + l];
        dp += __shfl_xor(dp, 16);
        dp += __shfl_xor(dp, 32);
        rden[j] = 1.f / (dp + 1e-6f);
    }

    // rows=e (quad*4+r), cols=n (lm): 4 consecutive e -> 8B store to attnT[n][c]
    #pragma unroll
    for (int i = 0; i < 4; ++i) {
        int e = i * 16 + quad * 4;
        #pragma unroll
        for (int j = 0; j < 4; ++j) {
            int n = nb + j * 16 + lm;
            ushort4v pk;
            #pragma unroll
            for (int r = 0; r < 4; ++r)
                pk[r] = f2bf(acc[i][j][r] * rden[j]);
            *(ushort4v*)(attnT + ((size_t)b * NSP + n) * CCH + h * 64 + e) = pk;
        }
    }
}

// ---------------------------------------------------------------------------
// Kernel 9: proj GEMM. mfma(attnT, w) -> rows=n. float4 bias+resid epilogue.
__global__ __launch_bounds__(256) void gemm_proj(const unsigned short* __restrict__ A,
                                                 const unsigned short* __restrict__ Bt,
                                                 const float* __restrict__ bias,
                                                 const float* __restrict__ resid,
                                                 float* __restrict__ outF) {
    const int n0 = blockIdx.x * 128;
    const int o0 = blockIdx.y * 128;
    const int b  = blockIdx.z;
    const int t  = threadIdx.x;
    const int wv = t >> 6, ln = t & 63;
    const int quad = ln >> 4, lm = ln & 15;
    const int wo = (wv >> 1) * 64, wn = (wv & 1) * 64;

    __shared__ __align__(16) unsigned short As[128 * 32];
    __shared__ __align__(16) unsigned short Bs[128 * 32];

    float4v acc[4][4];
    #pragma unroll
    for (int i = 0; i < 4; ++i)
        #pragma unroll
        for (int j = 0; j < 4; ++j) acc[i][j] = {0.f, 0.f, 0.f, 0.f};

    const unsigned short* aBase = A + (size_t)o0 * CCH;
    const unsigned short* bBase = Bt + ((size_t)b * NSP + n0) * CCH;

    const int srow = ln >> 2;
    const int scs  = ((ln & 3) ^ ((ln >> 3) & 3)) * 8;
    const int sc8  = (quad ^ ((lm >> 1) & 3)) * 8;

    for (int k0 = 0; k0 < CCH; k0 += 32) {
        __syncthreads();
        GLOAD_LDS16(aBase + (size_t)(wv * 16 + srow) * CCH + k0 + scs,      As + wv * 512);
        GLOAD_LDS16(aBase + (size_t)(64 + wv * 16 + srow) * CCH + k0 + scs, As + 2048 + wv * 512);
        GLOAD_LDS16(bBase + (size_t)(wv * 16 + srow) * CCH + k0 + scs,      Bs + wv * 512);
        GLOAD_LDS16(bBase + (size_t)(64 + wv * 16 + srow) * CCH + k0 + scs, Bs + 2048 + wv * 512);
        __syncthreads();

        short8 fw[4], fx[4];
        #pragma unroll
        for (int i = 0; i < 4; ++i)
            fw[i] = *(const short8*)(As + (wo + i * 16 + lm) * 32 + sc8);
        #pragma unroll
        for (int j = 0; j < 4; ++j)
            fx[j] = *(const short8*)(Bs + (wn + j * 16 + lm) * 32 + sc8);
        #pragma unroll
        for (int i = 0; i < 4; ++i)
            #pragma unroll
            for (int j = 0; j < 4; ++j)
                acc[i][j] = __builtin_amdgcn_mfma_f32_16x16x32_bf16(
                    fx[j], fw[i], acc[i][j], 0, 0, 0);
    }

    // rows=n (quad*4+r), cols=o (lm). float4 bias+resid epilogue.
    #pragma unroll
    for (int i = 0; i < 4; ++i) {
        int o = o0 + wo + i * 16 + lm;
        float bs = bias[o];
        #pragma unroll
        for (int j = 0; j < 4; ++j) {
            int n = n0 + wn + j * 16 + quad * 4;
            size_t off = ((size_t)b * CCH + o) * NSP + n;
            float4 rv = *(const float4*)(resid + off);
            float4 w = {acc[i][j][0] + bs + rv.x, acc[i][j][1] + bs + rv.y,
                        acc[i][j][2] + bs + rv.z, acc[i][j][3] + bs + rv.w};
            *(float4*)(outF + off) = w;
        }
    }
}

// ---------------------------------------------------------------------------
extern "C" void kernel_launch(void* const* d_in, const int* in_sizes, int n_in,
                              void* d_out, int out_size, void* d_ws, size_t ws_size,
                              hipStream_t stream) {
    const float* x      = (const float*)d_in[0];
    const float* gamma  = (const float*)d_in[1];
    const float* beta   = (const float*)d_in[2];
    const float* qkv_w  = (const float*)d_in[3];
    const float* qkv_b  = (const float*)d_in[4];
    const float* proj_w = (const float*)d_in[5];
    const float* proj_b = (const float*)d_in[6];
    float* out = (float*)d_out;

    // workspace layout (float units)
    float* ws   = (float*)d_ws;
    float* ss   = ws;                                   //    8192
    float* ksum = ss + 8192;                            //    4096
    float* kvp  = ksum + 4096;                          // 1048576
    unsigned short* xnT   = (unsigned short*)(kvp + 4 * 64 * 64 * 64);
    unsigned short* qT    = xnT + (size_t)BATCH * NSP * CCH;
    unsigned short* kb    = qT  + (size_t)BATCH * NSP * CCH;
    unsigned short* vb    = kb  + (size_t)BATCH * NSP * CCH;
    unsigned short* attnT = vb  + (size_t)BATCH * NSP * CCH;
    unsigned short* kvTb  = attnT + (size_t)BATCH * NSP * CCH;
    unsigned short* wqb   = kvTb + (size_t)64 * 64 * 64;
    unsigned short* wpb   = wqb + (size_t)O1 * CCH;

    gn_stats<<<BATCH * NGROUPS, 256, 0, stream>>>(x, gamma, beta, ss);
    conv_w<<<(O1 * CCH + CCH * CCH) / 4 / 256, 256, 0, stream>>>(qkv_w, proj_w, wqb, wpb, ksum);
    xnT_kernel<<<dim3(NSP / 64, CCH / 64, BATCH), 256, 0, stream>>>(x, ss, xnT);

    gemm_q <<<dim3(NSP / 128, 4, BATCH), 256, 0, stream>>>(wqb, xnT, qkv_b, qT);
    gemm_kv<<<dim3(NSP / 128, 8, BATCH), 256, 0, stream>>>(wqb, xnT, qkv_b, kb, vb, ksum);

    kv_mfma<<<dim3(4, 64), 256, 0, stream>>>(kb, vb, kvp);
    kv_reduce<<<256, 256, 0, stream>>>(kvp, kvTb);
    attn_mfma<<<dim3(NSP / 256, 64), 256, 0, stream>>>(qT, kvTb, ksum, attnT);

    gemm_proj<<<dim3(NSP / 128, CCH / 128, BATCH), 256, 0, stream>>>(
        wpb, attnT, proj_b, x, out);
}

// Round 5
// 295.887 us; speedup vs baseline: 3.8238x; 1.0285x over previous
//
#include <hip/hip_runtime.h>
#include <math.h>

#define BATCH   8
#define CCH     512
#define NHEADS  8
#define HD      64
#define NGROUPS 32
#define CPG     16
#define NSP     4096      // H*W
#define O1      1536      // 3*C

typedef __attribute__((ext_vector_type(8))) short          short8;
typedef __attribute__((ext_vector_type(8))) unsigned short ushort8;
typedef __attribute__((ext_vector_type(4))) unsigned short ushort4v;
typedef __attribute__((ext_vector_type(4))) float          float4v;

#define GLOAD_LDS16(g, s) __builtin_amdgcn_global_load_lds(                   \
    (const __attribute__((address_space(1))) void*)(g),                       \
    (__attribute__((address_space(3))) void*)(s), 16, 0, 0)

// ---------------------------------------------------------------------------
__device__ __forceinline__ float phi_act(float v) {   // elu(x)+1
    return v > 0.f ? v + 1.f : __expf(v);
}
__device__ __forceinline__ unsigned short f2bf(float f) {  // RNE fp32->bf16
    union { float f; unsigned int u; } c; c.f = f;
    unsigned int u = c.u;
    u += 0x7fffu + ((u >> 16) & 1u);
    return (unsigned short)(u >> 16);
}
__device__ __forceinline__ float bf2f(unsigned short s) {
    union { unsigned int u; float f; } c; c.u = ((unsigned int)s) << 16;
    return c.f;
}

// BK=64 LDS swizzle (rows of 128 B = 8 chunks of 16 B):
//  chunk c of row r lives at physical chunk c ^ (r & 7).
//  Staging: 1KB slab = 8 rows; lane ln writes physical (row=ln>>3, chunk=ln&7)
//    so it fetches GLOBAL chunk (ln&7) ^ (ln>>3).
//  Fragment read (quad,lm,kk): logical chunk kk*4+quad of row rb+lm (rb%16==0)
//    -> physical chunk (kk*4+quad) ^ (lm&7).  Worst 2 lanes/bank-group = free.

// ---------------------------------------------------------------------------
// Kernel 1: GroupNorm statistics -> per-(b,c) scale/shift
__global__ __launch_bounds__(256) void gn_stats(const float* __restrict__ x,
                                                const float* __restrict__ gamma,
                                                const float* __restrict__ beta,
                                                float* __restrict__ ss) {
    const int bg = blockIdx.x;
    const int t  = threadIdx.x;
    const float* base = x + (size_t)bg * (CPG * NSP);
    float s = 0.f, s2 = 0.f;
    #pragma unroll 4
    for (int i = 0; i < 64; ++i) {
        float4 v = *(const float4*)(base + (i * 256 + t) * 4);
        s  += v.x + v.y + v.z + v.w;
        s2 += v.x * v.x + v.y * v.y + v.z * v.z + v.w * v.w;
    }
    __shared__ float r1[256], r2[256];
    r1[t] = s; r2[t] = s2;
    __syncthreads();
    for (int off = 128; off > 0; off >>= 1) {
        if (t < off) { r1[t] += r1[t + off]; r2[t] += r2[t + off]; }
        __syncthreads();
    }
    if (t < CPG) {
        const float inv = 1.f / 65536.f;
        float mean = r1[0] * inv;
        float var  = r2[0] * inv - mean * mean;
        float rstd = rsqrtf(var + 1e-5f);
        int b = bg / NGROUPS, g = bg % NGROUPS;
        int c = g * CPG + t;
        float sc = gamma[c] * rstd;
        float sh = beta[c] - mean * sc;
        ss[(b * CCH + c) * 2]     = sc;
        ss[(b * CCH + c) * 2 + 1] = sh;
    }
}

// ---------------------------------------------------------------------------
// Kernel 2: weights fp32 -> bf16; block 0 also zeroes ksum (atomic target).
__global__ __launch_bounds__(256) void conv_w(const float* __restrict__ qw,
                                              const float* __restrict__ pw,
                                              unsigned short* __restrict__ qwb,
                                              unsigned short* __restrict__ pwb,
                                              float* __restrict__ ksum) {
    int i = (blockIdx.x * 256 + threadIdx.x) * 4;
    if (i < O1 * CCH) {
        float4 v = *(const float4*)(qw + i);
        unsigned short o[4] = {f2bf(v.x), f2bf(v.y), f2bf(v.z), f2bf(v.w)};
        *(uint2*)(qwb + i) = *(uint2*)o;
    } else {
        int j = i - O1 * CCH;
        float4 v = *(const float4*)(pw + j);
        unsigned short o[4] = {f2bf(v.x), f2bf(v.y), f2bf(v.z), f2bf(v.w)};
        *(uint2*)(pwb + j) = *(uint2*)o;
    }
    if (blockIdx.x == 0) {
        float4 z = {0.f, 0.f, 0.f, 0.f};
        #pragma unroll
        for (int l = 0; l < 4; ++l)
            *(float4*)(ksum + (l * 256 + threadIdx.x) * 4) = z;
    }
}

// ---------------------------------------------------------------------------
// Kernel 3: xnT[b][n][c] bf16 = GroupNorm(x)[b][c][n] transposed.
__global__ __launch_bounds__(256) void xnT_kernel(const float* __restrict__ x,
                                                  const float* __restrict__ ss,
                                                  unsigned short* __restrict__ xnT) {
    const int n0 = blockIdx.x * 64, c0 = blockIdx.y * 64, b = blockIdx.z;
    const int t = threadIdx.x;
    __shared__ float tile[64][65];
    const float* xb  = x + ((size_t)b * CCH + c0) * NSP + n0;
    const float* ssb = ss + b * CCH * 2;

    const int lr = t / 16, lc = (t % 16) * 4;
    #pragma unroll
    for (int j = 0; j < 4; ++j) {
        int cr = j * 16 + lr;
        float4 v = *(const float4*)(xb + (size_t)cr * NSP + lc);
        float sc = ssb[(c0 + cr) * 2], sh = ssb[(c0 + cr) * 2 + 1];
        tile[cr][lc + 0] = v.x * sc + sh;
        tile[cr][lc + 1] = v.y * sc + sh;
        tile[cr][lc + 2] = v.z * sc + sh;
        tile[cr][lc + 3] = v.w * sc + sh;
    }
    __syncthreads();
    #pragma unroll
    for (int j = 0; j < 2; ++j) {
        int wd = j * 256 + t;
        int n  = wd >> 3;
        int cb = (wd & 7) * 8;
        ushort8 o;
        #pragma unroll
        for (int i = 0; i < 8; ++i) o[i] = f2bf(tile[cb + i][n]);
        *(ushort8*)(xnT + ((size_t)b * NSP + n0 + n) * CCH + c0 + cb) = o;
    }
}

// ---------------------------------------------------------------------------
// Kernel 4: q GEMM (BK=64). mfma(w, x) -> rows=o. phi, 8B stores qT[b][n][c].
__global__ __launch_bounds__(256) void gemm_q(const unsigned short* __restrict__ A,
                                              const unsigned short* __restrict__ Bt,
                                              const float* __restrict__ bias,
                                              unsigned short* __restrict__ qT) {
    const int n0 = blockIdx.x * 128;
    const int o0 = blockIdx.y * 128;
    const int b  = blockIdx.z;
    const int t  = threadIdx.x;
    const int wv = t >> 6, ln = t & 63;
    const int quad = ln >> 4, lm = ln & 15;
    const int wo = (wv >> 1) * 64, wn = (wv & 1) * 64;

    __shared__ __align__(16) unsigned short As[128 * 64];
    __shared__ __align__(16) unsigned short Bs[128 * 64];

    float4v acc[4][4];
    #pragma unroll
    for (int i = 0; i < 4; ++i)
        #pragma unroll
        for (int j = 0; j < 4; ++j) acc[i][j] = {0.f, 0.f, 0.f, 0.f};

    const unsigned short* aBase = A + (size_t)o0 * CCH;
    const unsigned short* bBase = Bt + ((size_t)b * NSP + n0) * CCH;

    const int srow8 = ln >> 3;                        // row within slab
    const int scs   = ((ln & 7) ^ srow8) * 8;         // staging inverse swizzle
    const int lmp   = (lm & 7);                       // fragment row parity

    for (int k0 = 0; k0 < CCH; k0 += 64) {
        __syncthreads();
        #pragma unroll
        for (int i = 0; i < 4; ++i) {
            int slab = wv + i * 4;                    // 0..15, 8 rows each
            GLOAD_LDS16(aBase + (size_t)(slab * 8 + srow8) * CCH + k0 + scs,
                        As + slab * 512);
            GLOAD_LDS16(bBase + (size_t)(slab * 8 + srow8) * CCH + k0 + scs,
                        Bs + slab * 512);
        }
        __syncthreads();
        #pragma unroll
        for (int kk = 0; kk < 2; ++kk) {
            const int sc8 = ((kk * 4 + quad) ^ lmp) * 8;
            short8 fw[4], fx[4];
            #pragma unroll
            for (int i = 0; i < 4; ++i)
                fw[i] = *(const short8*)(As + (wo + i * 16 + lm) * 64 + sc8);
            #pragma unroll
            for (int j = 0; j < 4; ++j)
                fx[j] = *(const short8*)(Bs + (wn + j * 16 + lm) * 64 + sc8);
            #pragma unroll
            for (int i = 0; i < 4; ++i)
                #pragma unroll
                for (int j = 0; j < 4; ++j)
                    acc[i][j] = __builtin_amdgcn_mfma_f32_16x16x32_bf16(
                        fw[i], fx[j], acc[i][j], 0, 0, 0);
        }
    }

    // rows=o (quad*4+r), cols=n (lm). phi, store 4 consecutive o.
    #pragma unroll
    for (int i = 0; i < 4; ++i) {
        int ob = o0 + wo + i * 16 + quad * 4;
        float4 b4 = *(const float4*)(bias + ob);
        float bs[4] = {b4.x, b4.y, b4.z, b4.w};
        #pragma unroll
        for (int j = 0; j < 4; ++j) {
            int n = n0 + wn + j * 16 + lm;
            ushort4v pk;
            #pragma unroll
            for (int r = 0; r < 4; ++r)
                pk[r] = f2bf(phi_act(acc[i][j][r] + bs[r]));
            *(ushort4v*)(qT + ((size_t)b * NSP + n) * CCH + ob) = pk;
        }
    }
}

// ---------------------------------------------------------------------------
// Kernel 5: k/v GEMM (BK=64). mfma(x, w) -> rows=n. stores kb/vb[b][c][n];
// phi + ksum atomics for k. grid.y: 0..3 -> k, 4..7 -> v.
__global__ __launch_bounds__(256) void gemm_kv(const unsigned short* __restrict__ A,
                                               const unsigned short* __restrict__ Bt,
                                               const float* __restrict__ bias,
                                               unsigned short* __restrict__ kb,
                                               unsigned short* __restrict__ vb,
                                               float* __restrict__ ksum) {
    const int n0 = blockIdx.x * 128;
    const int o0 = 512 + blockIdx.y * 128;
    const int b  = blockIdx.z;
    const int t  = threadIdx.x;
    const int wv = t >> 6, ln = t & 63;
    const int quad = ln >> 4, lm = ln & 15;
    const int wo = (wv >> 1) * 64, wn = (wv & 1) * 64;

    __shared__ __align__(16) unsigned short As[128 * 64];
    __shared__ __align__(16) unsigned short Bs[128 * 64];

    float4v acc[4][4];
    #pragma unroll
    for (int i = 0; i < 4; ++i)
        #pragma unroll
        for (int j = 0; j < 4; ++j) acc[i][j] = {0.f, 0.f, 0.f, 0.f};

    const unsigned short* aBase = A + (size_t)o0 * CCH;
    const unsigned short* bBase = Bt + ((size_t)b * NSP + n0) * CCH;

    const int srow8 = ln >> 3;
    const int scs   = ((ln & 7) ^ srow8) * 8;
    const int lmp   = (lm & 7);

    for (int k0 = 0; k0 < CCH; k0 += 64) {
        __syncthreads();
        #pragma unroll
        for (int i = 0; i < 4; ++i) {
            int slab = wv + i * 4;
            GLOAD_LDS16(aBase + (size_t)(slab * 8 + srow8) * CCH + k0 + scs,
                        As + slab * 512);
            GLOAD_LDS16(bBase + (size_t)(slab * 8 + srow8) * CCH + k0 + scs,
                        Bs + slab * 512);
        }
        __syncthreads();
        #pragma unroll
        for (int kk = 0; kk < 2; ++kk) {
            const int sc8 = ((kk * 4 + quad) ^ lmp) * 8;
            short8 fw[4], fx[4];
            #pragma unroll
            for (int i = 0; i < 4; ++i)
                fw[i] = *(const short8*)(As + (wo + i * 16 + lm) * 64 + sc8);
            #pragma unroll
            for (int j = 0; j < 4; ++j)
                fx[j] = *(const short8*)(Bs + (wn + j * 16 + lm) * 64 + sc8);
            #pragma unroll
            for (int i = 0; i < 4; ++i)
                #pragma unroll
                for (int j = 0; j < 4; ++j)
                    acc[i][j] = __builtin_amdgcn_mfma_f32_16x16x32_bf16(
                        fx[j], fw[i], acc[i][j], 0, 0, 0);
        }
    }

    // rows=n (quad*4+r), cols=o (lm). store 4 consecutive n.
    const bool isk = (o0 < 1024);
    unsigned short* dst = isk ? kb : vb;
    const int cb0 = o0 - (isk ? 512 : 1024);
    #pragma unroll
    for (int i = 0; i < 4; ++i) {
        int o = o0 + wo + i * 16 + lm;
        int c = cb0 + wo + i * 16 + lm;
        float bs = bias[o];
        float ksp = 0.f;
        #pragma unroll
        for (int j = 0; j < 4; ++j) {
            int n = n0 + wn + j * 16 + quad * 4;
            ushort4v pk;
            #pragma unroll
            for (int r = 0; r < 4; ++r) {
                float v = acc[i][j][r] + bs;
                if (isk) { v = phi_act(v); ksp += v; }
                pk[r] = f2bf(v);
            }
            *(ushort4v*)(dst + ((size_t)b * CCH + c) * NSP + n) = pk;
        }
        if (isk) {
            ksp += __shfl_xor(ksp, 16);
            ksp += __shfl_xor(ksp, 32);
            if (quad == 0) atomicAdd(ksum + b * CCH + c, ksp);
        }
    }
}

// ---------------------------------------------------------------------------
// Kernel 6: kv partials via MFMA. kv[d][e] = sum_n k[d][n]*v[e][n].
__global__ __launch_bounds__(256) void kv_mfma(const unsigned short* __restrict__ kb,
                                               const unsigned short* __restrict__ vb,
                                               float* __restrict__ kvp) {
    const int chunk = blockIdx.x, bh = blockIdx.y;
    const int b = bh >> 3, h = bh & 7;
    const int t = threadIdx.x;
    const int wv = t >> 6, ln = t & 63;
    const int quad = ln >> 4, lm = ln & 15;
    const int wd = (wv >> 1) * 32, we = (wv & 1) * 32;

    __shared__ __align__(16) unsigned short kt[2 * 64 * 32];  // [kk][d][32n]
    __shared__ __align__(16) unsigned short vt[2 * 64 * 32];

    float4v acc[2][2];
    #pragma unroll
    for (int i = 0; i < 2; ++i)
        #pragma unroll
        for (int j = 0; j < 2; ++j) acc[i][j] = {0.f, 0.f, 0.f, 0.f};

    const unsigned short* kbase = kb + ((size_t)b * CCH + h * 64) * NSP + chunk * 1024;
    const unsigned short* vbase = vb + ((size_t)b * CCH + h * 64) * NSP + chunk * 1024;
    const int srow = ln >> 2;
    const int scs  = ((ln & 3) ^ ((ln >> 3) & 3)) * 8;
    const int sc8  = (quad ^ ((lm >> 1) & 3)) * 8;

    for (int it = 0; it < 16; ++it) {
        int noff = it * 64;
        __syncthreads();
        GLOAD_LDS16(kbase + (size_t)(wv * 16 + srow) * NSP + noff + scs,      kt + wv * 512);
        GLOAD_LDS16(kbase + (size_t)(wv * 16 + srow) * NSP + noff + 32 + scs, kt + 2048 + wv * 512);
        GLOAD_LDS16(vbase + (size_t)(wv * 16 + srow) * NSP + noff + scs,      vt + wv * 512);
        GLOAD_LDS16(vbase + (size_t)(wv * 16 + srow) * NSP + noff + 32 + scs, vt + 2048 + wv * 512);
        __syncthreads();
        #pragma unroll
        for (int kk = 0; kk < 2; ++kk) {
            short8 a0 = *(const short8*)(kt + kk * 2048 + (wd + lm) * 32 + sc8);
            short8 a1 = *(const short8*)(kt + kk * 2048 + (wd + 16 + lm) * 32 + sc8);
            short8 b0 = *(const short8*)(vt + kk * 2048 + (we + lm) * 32 + sc8);
            short8 b1 = *(const short8*)(vt + kk * 2048 + (we + 16 + lm) * 32 + sc8);
            acc[0][0] = __builtin_amdgcn_mfma_f32_16x16x32_bf16(a0, b0, acc[0][0], 0, 0, 0);
            acc[0][1] = __builtin_amdgcn_mfma_f32_16x16x32_bf16(a0, b1, acc[0][1], 0, 0, 0);
            acc[1][0] = __builtin_amdgcn_mfma_f32_16x16x32_bf16(a1, b0, acc[1][0], 0, 0, 0);
            acc[1][1] = __builtin_amdgcn_mfma_f32_16x16x32_bf16(a1, b1, acc[1][1], 0, 0, 0);
        }
    }
    // rows=d (quad*4+r), cols=e (lm) -> store [e][d], 4 consecutive d.
    #pragma unroll
    for (int i = 0; i < 2; ++i)
        #pragma unroll
        for (int j = 0; j < 2; ++j) {
            int e = we + j * 16 + lm;
            int d = wd + i * 16 + quad * 4;
            float4 r = {acc[i][j][0], acc[i][j][1], acc[i][j][2], acc[i][j][3]};
            *(float4*)(kvp + ((size_t)(chunk * 64 + bh) * 64 + e) * 64 + d) = r;
        }
}

// ---------------------------------------------------------------------------
// Kernel 7: reduce 4 chunk partials -> kvTb[bh][e][d] bf16.
__global__ __launch_bounds__(256) void kv_reduce(const float* __restrict__ kvp,
                                                 unsigned short* __restrict__ kvTb) {
    int idx4 = (blockIdx.x * 256 + threadIdx.x) * 4;   // over 64*64*64
    float4 s = {0.f, 0.f, 0.f, 0.f};
    #pragma unroll
    for (int p = 0; p < 4; ++p) {
        float4 v = *(const float4*)(kvp + (size_t)p * (64 * 64 * 64) + idx4);
        s.x += v.x; s.y += v.y; s.z += v.z; s.w += v.w;
    }
    ushort4v o = {f2bf(s.x), f2bf(s.y), f2bf(s.z), f2bf(s.w)};
    *(ushort4v*)(kvTb + idx4) = o;
}

// ---------------------------------------------------------------------------
// Kernel 8: attn via MFMA. out[n][e] = (sum_d qT[n][d]*kvT[e][d]) / den[n].
__global__ __launch_bounds__(256) void attn_mfma(const unsigned short* __restrict__ qT,
                                                 const unsigned short* __restrict__ kvTb,
                                                 const float* __restrict__ ksum,
                                                 unsigned short* __restrict__ attnT) {
    const int n0 = blockIdx.x * 256;
    const int bh = blockIdx.y;
    const int b = bh >> 3, h = bh & 7;
    const int t = threadIdx.x;
    const int wv = t >> 6, ln = t & 63;
    const int quad = ln >> 4, lm = ln & 15;
    const int nb = n0 + wv * 64;

    __shared__ __align__(16) unsigned short kvs[64 * 72];
    __shared__ float kss[64];

    #pragma unroll
    for (int l = 0; l < 2; ++l) {
        int ch = l * 256 + t;            // 512 chunks of 8 ushorts
        int e = ch >> 3, c8 = ch & 7;
        *(ushort8*)(kvs + e * 72 + c8 * 8) =
            *(const ushort8*)(kvTb + (size_t)bh * 4096 + ch * 8);
    }
    if (t < 64) kss[t] = ksum[b * CCH + h * 64 + t];
    __syncthreads();

    short8 bq[4][2];
    #pragma unroll
    for (int j = 0; j < 4; ++j)
        #pragma unroll
        for (int kk = 0; kk < 2; ++kk) {
            int n = nb + j * 16 + lm;
            bq[j][kk] = *(const short8*)(qT + ((size_t)b * NSP + n) * CCH +
                                         h * 64 + kk * 32 + quad * 8);
        }
    short8 ak[4][2];
    #pragma unroll
    for (int i = 0; i < 4; ++i)
        #pragma unroll
        for (int kk = 0; kk < 2; ++kk)
            ak[i][kk] = *(const short8*)(kvs + (i * 16 + lm) * 72 + kk * 32 + quad * 8);

    float4v acc[4][4];
    #pragma unroll
    for (int i = 0; i < 4; ++i)
        #pragma unroll
        for (int j = 0; j < 4; ++j) acc[i][j] = {0.f, 0.f, 0.f, 0.f};
    #pragma unroll
    for (int kk = 0; kk < 2; ++kk)
        #pragma unroll
        for (int i = 0; i < 4; ++i)
            #pragma unroll
            for (int j = 0; j < 4; ++j)
                acc[i][j] = __builtin_amdgcn_mfma_f32_16x16x32_bf16(
                    ak[i][kk], bq[j][kk], acc[i][j], 0, 0, 0);

    // denominators: den[n=nb+j*16+lm] = sum_d q[n][d]*ksum[d]
    float rden[4];
    #pragma unroll
    for (int j = 0; j < 4; ++j) {
        float dp = 0.f;
        #pragma unroll
        for (int kk = 0; kk < 2; ++kk)
            #pragma unroll
            for (int l = 0; l < 8; ++l)
                dp += bf2f((unsigned short)bq[j][kk][l]) * kss[kk * 32 + quad * 8 + l];
        dp += __shfl_xor(dp, 16);
        dp += __shfl_xor(dp, 32);
        rden[j] = 1.f / (dp + 1e-6f);
    }

    // rows=e (quad*4+r), cols=n (lm): 4 consecutive e -> 8B store to attnT[n][c]
    #pragma unroll
    for (int i = 0; i < 4; ++i) {
        int e = i * 16 + quad * 4;
        #pragma unroll
        for (int j = 0; j < 4; ++j) {
            int n = nb + j * 16 + lm;
            ushort4v pk;
            #pragma unroll
            for (int r = 0; r < 4; ++r)
                pk[r] = f2bf(acc[i][j][r] * rden[j]);
            *(ushort4v*)(attnT + ((size_t)b * NSP + n) * CCH + h * 64 + e) = pk;
        }
    }
}

// ---------------------------------------------------------------------------
// Kernel 9: proj GEMM (BK=64). mfma(attnT, w) -> rows=n. float4 bias+resid.
__global__ __launch_bounds__(256) void gemm_proj(const unsigned short* __restrict__ A,
                                                 const unsigned short* __restrict__ Bt,
                                                 const float* __restrict__ bias,
                                                 const float* __restrict__ resid,
                                                 float* __restrict__ outF) {
    const int n0 = blockIdx.x * 128;
    const int o0 = blockIdx.y * 128;
    const int b  = blockIdx.z;
    const int t  = threadIdx.x;
    const int wv = t >> 6, ln = t & 63;
    const int quad = ln >> 4, lm = ln & 15;
    const int wo = (wv >> 1) * 64, wn = (wv & 1) * 64;

    __shared__ __align__(16) unsigned short As[128 * 64];
    __shared__ __align__(16) unsigned short Bs[128 * 64];

    float4v acc[4][4];
    #pragma unroll
    for (int i = 0; i < 4; ++i)
        #pragma unroll
        for (int j = 0; j < 4; ++j) acc[i][j] = {0.f, 0.f, 0.f, 0.f};

    const unsigned short* aBase = A + (size_t)o0 * CCH;
    const unsigned short* bBase = Bt + ((size_t)b * NSP + n0) * CCH;

    const int srow8 = ln >> 3;
    const int scs   = ((ln & 7) ^ srow8) * 8;
    const int lmp   = (lm & 7);

    for (int k0 = 0; k0 < CCH; k0 += 64) {
        __syncthreads();
        #pragma unroll
        for (int i = 0; i < 4; ++i) {
            int slab = wv + i * 4;
            GLOAD_LDS16(aBase + (size_t)(slab * 8 + srow8) * CCH + k0 + scs,
                        As + slab * 512);
            GLOAD_LDS16(bBase + (size_t)(slab * 8 + srow8) * CCH + k0 + scs,
                        Bs + slab * 512);
        }
        __syncthreads();
        #pragma unroll
        for (int kk = 0; kk < 2; ++kk) {
            const int sc8 = ((kk * 4 + quad) ^ lmp) * 8;
            short8 fw[4], fx[4];
            #pragma unroll
            for (int i = 0; i < 4; ++i)
                fw[i] = *(const short8*)(As + (wo + i * 16 + lm) * 64 + sc8);
            #pragma unroll
            for (int j = 0; j < 4; ++j)
                fx[j] = *(const short8*)(Bs + (wn + j * 16 + lm) * 64 + sc8);
            #pragma unroll
            for (int i = 0; i < 4; ++i)
                #pragma unroll
                for (int j = 0; j < 4; ++j)
                    acc[i][j] = __builtin_amdgcn_mfma_f32_16x16x32_bf16(
                        fx[j], fw[i], acc[i][j], 0, 0, 0);
        }
    }

    // rows=n (quad*4+r), cols=o (lm). float4 bias+resid epilogue.
    #pragma unroll
    for (int i = 0; i < 4; ++i) {
        int o = o0 + wo + i * 16 + lm;
        float bs = bias[o];
        #pragma unroll
        for (int j = 0; j < 4; ++j) {
            int n = n0 + wn + j * 16 + quad * 4;
            size_t off = ((size_t)b * CCH + o) * NSP + n;
            float4 rv = *(const float4*)(resid + off);
            float4 w = {acc[i][j][0] + bs + rv.x, acc[i][j][1] + bs + rv.y,
                        acc[i][j][2] + bs + rv.z, acc[i][j][3] + bs + rv.w};
            *(float4*)(outF + off) = w;
        }
    }
}

// ---------------------------------------------------------------------------
extern "C" void kernel_launch(void* const* d_in, const int* in_sizes, int n_in,
                              void* d_out, int out_size, void* d_ws, size_t ws_size,
                              hipStream_t stream) {
    const float* x      = (const float*)d_in[0];
    const float* gamma  = (const float*)d_in[1];
    const float* beta   = (const float*)d_in[2];
    const float* qkv_w  = (const float*)d_in[3];
    const float* qkv_b  = (const float*)d_in[4];
    const float* proj_w = (const float*)d_in[5];
    const float* proj_b = (const float*)d_in[6];
    float* out = (float*)d_out;

    // workspace layout (float units)
    float* ws   = (float*)d_ws;
    float* ss   = ws;                                   //    8192
    float* ksum = ss + 8192;                            //    4096
    float* kvp  = ksum + 4096;                          // 1048576
    unsigned short* xnT   = (unsigned short*)(kvp + 4 * 64 * 64 * 64);
    unsigned short* qT    = xnT + (size_t)BATCH * NSP * CCH;
    unsigned short* kb    = qT  + (size_t)BATCH * NSP * CCH;
    unsigned short* vb    = kb  + (size_t)BATCH * NSP * CCH;
    unsigned short* attnT = vb  + (size_t)BATCH * NSP * CCH;
    unsigned short* kvTb  = attnT + (size_t)BATCH * NSP * CCH;
    unsigned short* wqb   = kvTb + (size_t)64 * 64 * 64;
    unsigned short* wpb   = wqb + (size_t)O1 * CCH;

    gn_stats<<<BATCH * NGROUPS, 256, 0, stream>>>(x, gamma, beta, ss);
    conv_w<<<(O1 * CCH + CCH * CCH) / 4 / 256, 256, 0, stream>>>(qkv_w, proj_w, wqb, wpb, ksum);
    xnT_kernel<<<dim3(NSP / 64, CCH / 64, BATCH), 256, 0, stream>>>(x, ss, xnT);

    gemm_q <<<dim3(NSP / 128, 4, BATCH), 256, 0, stream>>>(wqb, xnT, qkv_b, qT);
    gemm_kv<<<dim3(NSP / 128, 8, BATCH), 256, 0, stream>>>(wqb, xnT, qkv_b, kb, vb, ksum);

    kv_mfma<<<dim3(4, 64), 256, 0, stream>>>(kb, vb, kvp);
    kv_reduce<<<256, 256, 0, stream>>>(kvp, kvTb);
    attn_mfma<<<dim3(NSP / 256, 64), 256, 0, stream>>>(qT, kvTb, ksum, attnT);

    gemm_proj<<<dim3(NSP / 128, CCH / 128, BATCH), 256, 0, stream>>>(
        wpb, attnT, proj_b, x, out);
}